// Round 2
// baseline (6341.900 us; speedup 1.0000x reference)
//
#include <hip/hip_runtime.h>
#include <cstdint>
#include <cmath>

#pragma clang fp contract(off)

#define N_OBS 2048
#define D_DIM 128
#define R_DIM 16
#define NSAMP 500

// ---- workspace layout (bytes) ----
#define WS_M     0        // 16 f32
#define WS_EY    64       // 128 f32
#define WS_GAIN  576      // 16*128 f32
#define WS_SCAL  8768     // scalars: [0]=trace_C, [1]=pconst, [2]=alpha0
#define WS_HC    8800     // 128*16 f32  (H@C)
#define WS_A     16992    // f64 [128][256] Gauss-Jordan augmented
#define WS_DIRI  279136   // 2048*16 f32
#define WS_QC    410208   // 2048 f32

// ---- f32 transcendentals computed through double (≈ correctly rounded, to
// match glibc/XLA-CPU which use double-internal f32 routines) ----
__device__ __forceinline__ float flog(float x)   { return (float)log((double)x); }
__device__ __forceinline__ float flog1p(float x) { return (float)log1p((double)x); }
__device__ __forceinline__ float fexp(float x)   { return (float)exp((double)x); }

// ---------------- Threefry-2x32, 20 rounds (JAX-compatible) ----------------
__device__ __forceinline__ void tf_block(uint32_t k0, uint32_t k1,
                                         uint32_t x0, uint32_t x1,
                                         uint32_t& o0, uint32_t& o1) {
  const uint32_t k2 = k0 ^ k1 ^ 0x1BD11BDAu;
  x0 += k0; x1 += k1;
#define TF_R(r) { x0 += x1; x1 = (x1 << (r)) | (x1 >> (32 - (r))); x1 ^= x0; }
  TF_R(13) TF_R(15) TF_R(26) TF_R(6)
  x0 += k1; x1 += k2 + 1u;
  TF_R(17) TF_R(29) TF_R(16) TF_R(24)
  x0 += k2; x1 += k0 + 2u;
  TF_R(13) TF_R(15) TF_R(26) TF_R(6)
  x0 += k0; x1 += k1 + 3u;
  TF_R(17) TF_R(29) TF_R(16) TF_R(24)
  x0 += k1; x1 += k2 + 4u;
  TF_R(13) TF_R(15) TF_R(26) TF_R(6)
  x0 += k2; x1 += k0 + 5u;
#undef TF_R
  o0 = x0; o1 = x1;
}

// scalar random_bits under threefry_partitionable: block over count (0,0), xor halves
__device__ __forceinline__ uint32_t rb32(uint32_t ka, uint32_t kb) {
  uint32_t o0, o1;
  tf_block(ka, kb, 0u, 0u, o0, o1);
  return o0 ^ o1;
}

// JAX uniform [0,1): randomize mantissa with exponent 1, subtract 1
__device__ __forceinline__ float u01(uint32_t bits) {
  uint32_t fb = (bits >> 9) | 0x3F800000u;
  return __uint_as_float(fb) - 1.0f;
}

// XLA f32 ErfInv polynomial (Giles) — HLO-level expansion, identical on CPU/GPU
__device__ __forceinline__ float erfinv_xla(float x) {
  float w = -flog1p(-(x * x));
  float p;
  if (w < 5.0f) {
    w = w - 2.5f;
    p = 2.81022636e-08f;
    p = 3.43273939e-07f + p * w;
    p = -3.5233877e-06f + p * w;
    p = -4.39150654e-06f + p * w;
    p = 0.00021858087f + p * w;
    p = -0.00125372503f + p * w;
    p = -0.00417768164f + p * w;
    p = 0.246640727f + p * w;
    p = 1.50140941f + p * w;
  } else {
    w = sqrtf(w) - 3.0f;
    p = -0.000200214257f;
    p = 0.000100950558f + p * w;
    p = 0.00134934322f + p * w;
    p = -0.00367342844f + p * w;
    p = 0.00573950773f + p * w;
    p = -0.0076224613f + p * w;
    p = 0.00943887047f + p * w;
    p = 1.00167406f + p * w;
    p = 2.83297682f + p * w;
  }
  return p * x;
}

// normal(key) = sqrt(2)*erfinv(uniform(lo=-0.99999994, hi=1))
__device__ __forceinline__ float normal_jax(uint32_t ka, uint32_t kb) {
  float f = u01(rb32(ka, kb));
  float u = f * 2.0f + (-0.99999994f);
  u = fmaxf(-0.99999994f, u);
  return 1.41421356f * erfinv_xla(u);
}

// _gamma_one(key_j, a, log_space=True) with key_j = TF((0,42), 0, jf)  [foldlike split]
__device__ float sample_loggamma(uint32_t jf, float a) {
  uint32_t ka, kb;
  tf_block(0u, 42u, 0u, jf, ka, kb);     // per-sample key

  // key, subkey = split(key)   (foldlike: block counts (0,0) and (0,1))
  uint32_t k1a, k1b, ska, skb;
  tf_block(ka, kb, 0u, 0u, k1a, k1b);
  tf_block(ka, kb, 0u, 1u, ska, skb);

  // log_boost source = -Exponential(subkey) = log1p(-uniform(subkey))
  float ef = u01(rb32(ska, skb));
  float log_samples = flog1p(-ef);

  bool boost = (a >= 1.0f);
  float a_orig = a;
  float aa = boost ? a : (a + 1.0f);
  float d = aa - 0.33333334f;
  float c = 0.33333334f / sqrtf(d);

  uint32_t kcx = k1a, kcy = k1b;
  float X = 0.0f, V = 1.0f;
  for (int it = 0; it < 256; ++it) {
    uint32_t kna, knb, xka, xkb, Uka, Ukb;
    tf_block(kcx, kcy, 0u, 0u, kna, knb);   // new carry key
    tf_block(kcx, kcy, 0u, 1u, xka, xkb);   // x_key
    tf_block(kcx, kcy, 0u, 2u, Uka, Ukb);   // U_key
    kcx = kna; kcy = knb;
    float x = 0.0f, v = -1.0f;
    for (int in = 0; in < 256; ++in) {
      uint32_t nxa, nxb, sxa, sxb;
      tf_block(xka, xkb, 0u, 0u, nxa, nxb); // carried x_key
      tf_block(xka, xkb, 0u, 1u, sxa, sxb); // subkey for normal
      xka = nxa; xkb = nxb;
      x = normal_jax(sxa, sxb);
      v = 1.0f + x * c;
      if (v > 0.0f) break;
    }
    X = x * x;
    V = (v * v) * v;
    float U = u01(rb32(Uka, Ukb));
    // continue while BOTH hold; accept (break) when either fails.
    // squeeze: U >= 1 - 0.0331*X*X   (X = x^2, so 0.0331*x^4)
    bool cond = (U >= 1.0f - 0.0331f * (X * X)) &&
                (flog(U) >= X * 0.5f + d * ((1.0f - V) + flog(V)));
    if (!cond) break;
  }
  float log_boost = (boost || log_samples == 0.0f) ? 0.0f
                                                   : log_samples * (1.0f / a_orig);
  return (flog(d) + flog(V)) + log_boost;
}

// ---------------- Kernel 1: LMMSE prep (1 block) ----------------
__global__ __launch_bounds__(256) void prep_kernel(const float* __restrict__ H,
                                                   const float* __restrict__ alpha,
                                                   char* __restrict__ ws) {
  float* m    = (float*)(ws + WS_M);
  float* EY   = (float*)(ws + WS_EY);
  float* gain = (float*)(ws + WS_GAIN);
  float* scal = (float*)(ws + WS_SCAL);
  float* HC   = (float*)(ws + WS_HC);
  double* A   = (double*)(ws + WS_A);

  __shared__ float sH[128 * 16];
  __shared__ float sC[16][16];
  __shared__ float sm[16];
  __shared__ double fac[128];
  __shared__ double spiv;

  int t = threadIdx.x;
  for (int i = t; i < 2048; i += 256) sH[i] = H[i];
  __syncthreads();

  if (t == 0) {
    float a0 = 0.0f;
    for (int j = 0; j < 16; ++j) a0 += alpha[j];
    float pc = lgammaf(a0);
    for (int j = 0; j < 16; ++j) pc -= lgammaf(alpha[j]);
    scal[2] = a0; scal[1] = pc;
    for (int j = 0; j < 16; ++j) { sm[j] = alpha[j] / a0; m[j] = sm[j]; }
  }
  __syncthreads();
  float a0 = scal[2];

  {
    int i = t >> 4, j = t & 15;
    float v = ((i == j) ? sm[i] : 0.0f) - sm[i] * sm[j];
    sC[i][j] = v / (a0 + 1.0f);
  }
  if (t < 128) {
    float acc = 0.0f;
    for (int j = 0; j < 16; ++j) acc += sH[t * 16 + j] * sm[j];
    EY[t] = acc;
  }
  __syncthreads();

  for (int idx = t; idx < 2048; idx += 256) {
    int dd = idx >> 4, j = idx & 15;
    float acc = 0.0f;
    for (int i = 0; i < 16; ++i) acc += sH[dd * 16 + i] * sC[i][j];
    HC[idx] = acc;
  }
  __syncthreads();

  for (int idx = t; idx < 16384; idx += 256) {
    int dd = idx >> 7, e = idx & 127;
    float acc = 0.0f;
    for (int j = 0; j < 16; ++j) acc += HC[dd * 16 + j] * sH[e * 16 + j];
    if (dd == e) acc += 0.01f;
    A[dd * 256 + e] = (double)acc;
    A[dd * 256 + 128 + e] = (dd == e) ? 1.0 : 0.0;
  }
  __syncthreads();

  // Gauss-Jordan in f64 (SPD -> no pivoting needed)
  for (int p = 0; p < 128; ++p) {
    if (t < 128) fac[t] = A[t * 256 + p];
    if (t == 0) spiv = 1.0 / A[p * 256 + p];
    __syncthreads();
    A[p * 256 + t] *= spiv;
    __syncthreads();
    {
      int r = t >> 1;
      int c0 = (t & 1) * 128;
      if (r != p) {
        double f = fac[r];
        const double* prow = &A[p * 256];
        double* rrow = &A[r * 256];
        for (int cc = c0; cc < c0 + 128; ++cc) rrow[cc] -= f * prow[cc];
      }
    }
    __syncthreads();
  }

  // gain[j][e] = sum_d HC[d][j] * inv[d][e]
  for (int idx = t; idx < 2048; idx += 256) {
    int j = idx >> 7, e = idx & 127;
    double acc = 0.0;
    for (int dd = 0; dd < 128; ++dd)
      acc += (double)HC[dd * 16 + j] * A[dd * 256 + 128 + e];
    gain[j * 128 + e] = (float)acc;
  }
  __syncthreads();

  if (t == 0) {
    float tr = 0.0f;
    for (int j = 0; j < 16; ++j) {
      float s2 = 0.0f;
      for (int dd = 0; dd < 128; ++dd) s2 += gain[j * 128 + dd] * HC[dd * 16 + j];
      tr += sC[j][j] - s2;
    }
    tr = fmaxf(tr, 0.0f) + 1e-6f;
    scal[0] = tr;
  }
}

// ---------------- Kernel 2: per-observation proposal concentrations ----------------
__global__ __launch_bounds__(256) void diri_kernel(const float* __restrict__ y,
                                                   char* __restrict__ ws) {
  float* m    = (float*)(ws + WS_M);
  float* EY   = (float*)(ws + WS_EY);
  float* gain = (float*)(ws + WS_GAIN);
  float* scal = (float*)(ws + WS_SCAL);
  float* diri = (float*)(ws + WS_DIRI);
  float* qc   = (float*)(ws + WS_QC);

  __shared__ float sg[16 * 128];
  __shared__ float sEY[128];
  __shared__ float sm[16];
  __shared__ float s_tr;

  int t = threadIdx.x;
  for (int i = t; i < 2048; i += 256) sg[i] = gain[i];
  if (t < 128) sEY[t] = EY[t];
  if (t < 16) sm[t] = m[t];
  if (t == 0) s_tr = scal[0];
  __syncthreads();

  int n = blockIdx.x * 256 + t;
  float tv[16];
  for (int j = 0; j < 16; ++j) tv[j] = sm[j];
  const float* yn = y + n * 128;
  for (int dd = 0; dd < 128; ++dd) {
    float dy = yn[dd] - sEY[dd];
    for (int j = 0; j < 16; ++j) tv[j] += dy * sg[j * 128 + dd];
  }
  float s = 0.0f;
  for (int j = 0; j < 16; ++j) { tv[j] = fmaxf(tv[j], 0.0f) + 1e-6f; s += tv[j]; }
  float ssq = 0.0f;
  for (int j = 0; j < 16; ++j) { tv[j] = tv[j] / s; ssq += tv[j] * tv[j]; }
  float k = (1.0f - ssq) / s_tr - 1.0f;
  float dsum = 0.0f, lgs = 0.0f;
  float* dn = diri + n * 16;
  for (int j = 0; j < 16; ++j) {
    float dj = fmaxf(k * tv[j], 0.0f) + 0.8f;
    dn[j] = dj; dsum += dj; lgs += lgammaf(dj);
  }
  qc[n] = lgammaf(dsum) - lgs;
}

// ---------------- Kernel 3: sampling + importance-weighted moments ----------------
__global__ __launch_bounds__(256) void main_kernel(const float* __restrict__ y,
                                                   const float* __restrict__ H,
                                                   const float* __restrict__ alpha,
                                                   const char* __restrict__ ws,
                                                   float* __restrict__ out) {
  const float* diri = (const float*)(ws + WS_DIRI);
  const float* qc   = (const float*)(ws + WS_QC);
  const float* scal = (const float*)(ws + WS_SCAL);

  __shared__ float sHt[16][128];     // H transposed: sHt[j][d]
  __shared__ float sy[128];
  __shared__ float sdiri[16], salpha[16];
  __shared__ float slg[16][16];
  __shared__ float sz[16][17];       // z samples for 16 h's (+pad)
  __shared__ float red_q[256], red_p[256], red_s[256];
  __shared__ float slw[16], swv[16];
  __shared__ float sM, sS, sFac, sqc, spc;

  int t = threadIdx.x;
  int n = blockIdx.x;
  int h_sub = t >> 4, j = t & 15;

  for (int i = t; i < 2048; i += 256) {
    int dd = i & 127, jj = i >> 7;
    sHt[jj][dd] = H[dd * 16 + jj];
  }
  if (t < 128) sy[t] = y[n * 128 + t];
  if (t < 16) { sdiri[t] = diri[n * 16 + t]; salpha[t] = alpha[t]; }
  if (t == 0) { sM = -INFINITY; sS = 0.0f; sFac = 1.0f; sqc = qc[n]; spc = scal[1]; }
  __syncthreads();

  float acc = 0.0f;     // zzy[k=h_sub][l=j]
  float zyacc = 0.0f;   // threads t<16 own zy[t]
  float dj1 = sdiri[j] - 1.0f;
  float aj1 = salpha[j] - 1.0f;

  for (int cch = 0; cch < 32; ++cch) {
    int h = cch * 16 + h_sub;
    bool valid = (h < NSAMP);
    float lg = 0.0f;
    if (valid) {
      uint32_t jf = (((uint32_t)h * 2048u + (uint32_t)n) << 4) | (uint32_t)j;
      lg = sample_loggamma(jf, sdiri[j]);
    }
    slg[h_sub][j] = lg;
    __syncthreads();

    // softmax over the 16 components of row h_sub
    float mx = -INFINITY;
    for (int jj = 0; jj < 16; ++jj) mx = fmaxf(mx, slg[h_sub][jj]);
    float se = 0.0f;
    for (int jj = 0; jj < 16; ++jj) se += fexp(slg[h_sub][jj] - mx);
    float z = valid ? (fexp(lg - mx) / se) : 0.0f;
    sz[h_sub][j] = z;
    float lz = flog(z);
    red_q[t] = dj1 * lz;
    red_p[t] = aj1 * lz;
    __syncthreads();

    // residual: thread covers d = j + 16*s, s=0..7
    float rs[8];
    for (int s8 = 0; s8 < 8; ++s8) rs[s8] = -sy[j + 16 * s8];
    for (int jj = 0; jj < 16; ++jj) {
      float zv = sz[h_sub][jj];
      for (int s8 = 0; s8 < 8; ++s8) rs[s8] += sHt[jj][j + 16 * s8] * zv;
    }
    float ss = 0.0f;
    for (int s8 = 0; s8 < 8; ++s8) ss += rs[s8] * rs[s8];
    red_s[t] = ss;
    __syncthreads();

    if (j == 0) {
      float q = 0.0f, p2 = 0.0f, s3 = 0.0f;
      for (int jj = 0; jj < 16; ++jj) {
        q  += red_q[h_sub * 16 + jj];
        p2 += red_p[h_sub * 16 + jj];
        s3 += red_s[h_sub * 16 + jj];
      }
      float pyz = s3 / (-0.02f);
      float lw = pyz + (p2 + spc) - (q + sqc);
      slw[h_sub] = valid ? lw : -INFINITY;
    }
    __syncthreads();

    if (t == 0) {
      float cmax = sM;
      for (int hh = 0; hh < 16; ++hh) cmax = fmaxf(cmax, slw[hh]);
      float f2 = fexp(sM - cmax);
      float Snew = sS * f2;
      for (int hh = 0; hh < 16; ++hh) {
        float w = fexp(slw[hh] - cmax);
        swv[hh] = w; Snew += w;
      }
      sM = cmax; sS = Snew; sFac = f2;
    }
    __syncthreads();

    float fc = sFac;
    float a2 = acc * fc;
    for (int hh = 0; hh < 16; ++hh) a2 += swv[hh] * sz[hh][h_sub] * sz[hh][j];
    acc = a2;
    if (t < 16) {
      float zv2 = zyacc * fc;
      for (int hh = 0; hh < 16; ++hh) zv2 += swv[hh] * sz[hh][t];
      zyacc = zv2;
    }
    __syncthreads();
  }

  float Sf = sS;
  if (t < 16) out[n * 16 + t] = zyacc / Sf;
  out[N_OBS * R_DIM + n * 256 + t] = acc / Sf;
}

extern "C" void kernel_launch(void* const* d_in, const int* in_sizes, int n_in,
                              void* d_out, int out_size, void* d_ws, size_t ws_size,
                              hipStream_t stream) {
  const float* y     = (const float*)d_in[0];
  const float* H     = (const float*)d_in[1];
  const float* alpha = (const float*)d_in[2];
  char* ws = (char*)d_ws;
  float* out = (float*)d_out;

  prep_kernel<<<1, 256, 0, stream>>>(H, alpha, ws);
  diri_kernel<<<8, 256, 0, stream>>>(y, ws);
  main_kernel<<<N_OBS, 256, 0, stream>>>(y, H, alpha, ws, out);
}

// Round 3
// 1485.183 us; speedup vs baseline: 4.2701x; 4.2701x over previous
//
#include <hip/hip_runtime.h>
#include <cstdint>
#include <cmath>

#pragma clang fp contract(off)

#define N_OBS 2048
#define D_DIM 128
#define R_DIM 16
#define NSAMP 500

// ---- workspace layout (bytes) ----
#define WS_M     0        // 16 f32
#define WS_EY    64       // 128 f32
#define WS_GAIN  576      // 16*128 f32
#define WS_SCAL  8768     // scalars: [0]=trace_C, [1]=pconst, [2]=alpha0
#define WS_DIRI  279136   // 2048*16 f32
#define WS_QC    410208   // 2048 f32

// ---- f32 transcendentals computed through double (≈ correctly rounded, to
// match glibc/XLA-CPU which use double-internal f32 routines) ----
__device__ __forceinline__ float flog(float x)   { return (float)log((double)x); }
__device__ __forceinline__ float flog1p(float x) { return (float)log1p((double)x); }
__device__ __forceinline__ float fexp(float x)   { return (float)exp((double)x); }

// ---------------- Threefry-2x32, 20 rounds (JAX-compatible) ----------------
__device__ __forceinline__ void tf_block(uint32_t k0, uint32_t k1,
                                         uint32_t x0, uint32_t x1,
                                         uint32_t& o0, uint32_t& o1) {
  const uint32_t k2 = k0 ^ k1 ^ 0x1BD11BDAu;
  x0 += k0; x1 += k1;
#define TF_R(r) { x0 += x1; x1 = (x1 << (r)) | (x1 >> (32 - (r))); x1 ^= x0; }
  TF_R(13) TF_R(15) TF_R(26) TF_R(6)
  x0 += k1; x1 += k2 + 1u;
  TF_R(17) TF_R(29) TF_R(16) TF_R(24)
  x0 += k2; x1 += k0 + 2u;
  TF_R(13) TF_R(15) TF_R(26) TF_R(6)
  x0 += k0; x1 += k1 + 3u;
  TF_R(17) TF_R(29) TF_R(16) TF_R(24)
  x0 += k1; x1 += k2 + 4u;
  TF_R(13) TF_R(15) TF_R(26) TF_R(6)
  x0 += k2; x1 += k0 + 5u;
#undef TF_R
  o0 = x0; o1 = x1;
}

// scalar random_bits under threefry_partitionable: block over count (0,0), xor halves
__device__ __forceinline__ uint32_t rb32(uint32_t ka, uint32_t kb) {
  uint32_t o0, o1;
  tf_block(ka, kb, 0u, 0u, o0, o1);
  return o0 ^ o1;
}

// JAX uniform [0,1): randomize mantissa with exponent 1, subtract 1
__device__ __forceinline__ float u01(uint32_t bits) {
  uint32_t fb = (bits >> 9) | 0x3F800000u;
  return __uint_as_float(fb) - 1.0f;
}

// XLA f32 ErfInv polynomial (Giles) — HLO-level expansion, identical on CPU/GPU
__device__ __forceinline__ float erfinv_xla(float x) {
  float w = -flog1p(-(x * x));
  float p;
  if (w < 5.0f) {
    w = w - 2.5f;
    p = 2.81022636e-08f;
    p = 3.43273939e-07f + p * w;
    p = -3.5233877e-06f + p * w;
    p = -4.39150654e-06f + p * w;
    p = 0.00021858087f + p * w;
    p = -0.00125372503f + p * w;
    p = -0.00417768164f + p * w;
    p = 0.246640727f + p * w;
    p = 1.50140941f + p * w;
  } else {
    w = sqrtf(w) - 3.0f;
    p = -0.000200214257f;
    p = 0.000100950558f + p * w;
    p = 0.00134934322f + p * w;
    p = -0.00367342844f + p * w;
    p = 0.00573950773f + p * w;
    p = -0.0076224613f + p * w;
    p = 0.00943887047f + p * w;
    p = 1.00167406f + p * w;
    p = 2.83297682f + p * w;
  }
  return p * x;
}

// normal(key) = sqrt(2)*erfinv(uniform(lo=-0.99999994, hi=1))
__device__ __forceinline__ float normal_jax(uint32_t ka, uint32_t kb) {
  float f = u01(rb32(ka, kb));
  float u = f * 2.0f + (-0.99999994f);
  u = fmaxf(-0.99999994f, u);
  return 1.41421356f * erfinv_xla(u);
}

// _gamma_one(key_j, a, log_space=True) with key_j = TF((0,42), 0, jf)  [foldlike split]
__device__ float sample_loggamma(uint32_t jf, float a) {
  uint32_t ka, kb;
  tf_block(0u, 42u, 0u, jf, ka, kb);     // per-sample key

  // key, subkey = split(key)   (foldlike: block counts (0,0) and (0,1))
  uint32_t k1a, k1b, ska, skb;
  tf_block(ka, kb, 0u, 0u, k1a, k1b);
  tf_block(ka, kb, 0u, 1u, ska, skb);

  // log_boost source = -Exponential(subkey) = log1p(-uniform(subkey))
  float ef = u01(rb32(ska, skb));
  float log_samples = flog1p(-ef);

  bool boost = (a >= 1.0f);
  float a_orig = a;
  float aa = boost ? a : (a + 1.0f);
  float d = aa - 0.33333334f;
  float c = 0.33333334f / sqrtf(d);

  uint32_t kcx = k1a, kcy = k1b;
  float X = 0.0f, V = 1.0f;
  for (int it = 0; it < 256; ++it) {
    uint32_t kna, knb, xka, xkb, Uka, Ukb;
    tf_block(kcx, kcy, 0u, 0u, kna, knb);   // new carry key
    tf_block(kcx, kcy, 0u, 1u, xka, xkb);   // x_key
    tf_block(kcx, kcy, 0u, 2u, Uka, Ukb);   // U_key
    kcx = kna; kcy = knb;
    float x = 0.0f, v = -1.0f;
    for (int in = 0; in < 256; ++in) {
      uint32_t nxa, nxb, sxa, sxb;
      tf_block(xka, xkb, 0u, 0u, nxa, nxb); // carried x_key
      tf_block(xka, xkb, 0u, 1u, sxa, sxb); // subkey for normal
      xka = nxa; xkb = nxb;
      x = normal_jax(sxa, sxb);
      v = 1.0f + x * c;
      if (v > 0.0f) break;
    }
    X = x * x;
    V = (v * v) * v;
    float U = u01(rb32(Uka, Ukb));
    // continue while BOTH hold; accept (break) when either fails.
    bool cond = (U >= 1.0f - 0.0331f * (X * X)) &&
                (flog(U) >= X * 0.5f + d * ((1.0f - V) + flog(V)));
    if (!cond) break;
  }
  float log_boost = (boost || log_samples == 0.0f) ? 0.0f
                                                   : log_samples * (1.0f / a_orig);
  return (flog(d) + flog(V)) + log_boost;
}

// ---------------- Kernel 1: LMMSE prep (1 block, Woodbury 16x16) ----------------
// gain = C H^T (sI + H C H^T)^-1  ==  (sI16 + C H^T H)^-1 C H^T   [push-through]
__global__ __launch_bounds__(256) void prep_kernel(const float* __restrict__ H,
                                                   const float* __restrict__ alpha,
                                                   char* __restrict__ ws) {
  float* m    = (float*)(ws + WS_M);
  float* EY   = (float*)(ws + WS_EY);
  float* gain = (float*)(ws + WS_GAIN);
  float* scal = (float*)(ws + WS_SCAL);

  __shared__ float sH[128 * 16];
  __shared__ float sC[16][16];
  __shared__ float sHC[128 * 16];    // (H C)[d][j], f32 to match reference path
  __shared__ float sm[16];
  __shared__ double sHtH[16][16];
  __shared__ double M[16][33];       // augmented [M | I], 32 cols + pad
  __shared__ double dfac[16];
  __shared__ double spiv;
  __shared__ int   spivrow;
  __shared__ float sgain[16 * 128];

  int t = threadIdx.x;
  for (int i = t; i < 2048; i += 256) sH[i] = H[i];
  __syncthreads();

  if (t == 0) {
    float a0 = 0.0f;
    for (int j = 0; j < 16; ++j) a0 += alpha[j];
    float pc = lgammaf(a0);
    for (int j = 0; j < 16; ++j) pc -= lgammaf(alpha[j]);
    scal[2] = a0; scal[1] = pc;
    for (int j = 0; j < 16; ++j) { sm[j] = alpha[j] / a0; m[j] = sm[j]; }
  }
  __syncthreads();
  float a0 = scal[2];

  {
    int i = t >> 4, j = t & 15;
    float v = ((i == j) ? sm[i] : 0.0f) - sm[i] * sm[j];
    sC[i][j] = v / (a0 + 1.0f);
  }
  if (t < 128) {
    float acc = 0.0f;
    for (int j = 0; j < 16; ++j) acc += sH[t * 16 + j] * sm[j];
    EY[t] = acc;
  }
  __syncthreads();

  // HC[d][j] = sum_i H[d][i] C[i][j]  (f32)
  for (int idx = t; idx < 2048; idx += 256) {
    int dd = idx >> 4, j = idx & 15;
    float acc = 0.0f;
    for (int i = 0; i < 16; ++i) acc += sH[dd * 16 + i] * sC[i][j];
    sHC[idx] = acc;
  }
  // HtH[i][j] = sum_d H[d][i] H[d][j]  (f64)
  {
    int i = t >> 4, j = t & 15;
    double acc = 0.0;
    for (int dd = 0; dd < 128; ++dd)
      acc += (double)sH[dd * 16 + i] * (double)sH[dd * 16 + j];
    sHtH[i][j] = acc;
  }
  __syncthreads();

  // M = sigma*I + C * HtH  (f64), augmented with I
  {
    int i = t >> 4, j = t & 15;
    double acc = (i == j) ? 0.01 : 0.0;
    for (int k = 0; k < 16; ++k) acc += (double)sC[i][k] * sHtH[k][j];
    M[i][j] = acc;
    M[i][16 + j] = (i == j) ? 1.0 : 0.0;
  }
  __syncthreads();

  // Gauss-Jordan with partial pivoting on 16x32 (f64, all-LDS)
  for (int p = 0; p < 16; ++p) {
    if (t == 0) {
      int best = p; double bv = fabs(M[p][p]);
      for (int r = p + 1; r < 16; ++r) {
        double v = fabs(M[r][p]);
        if (v > bv) { bv = v; best = r; }
      }
      spivrow = best;
    }
    __syncthreads();
    int pr = spivrow;
    double va = 0.0, vb = 0.0;
    if (t < 32 && pr != p) { va = M[p][t]; vb = M[pr][t]; }
    __syncthreads();
    if (t < 32 && pr != p) { M[p][t] = vb; M[pr][t] = va; }
    __syncthreads();
    if (t == 0) spiv = 1.0 / M[p][p];
    __syncthreads();
    if (t < 32) M[p][t] *= spiv;
    if (t < 16) dfac[t] = M[t][p];
    __syncthreads();
    {
      // 16 rows x 32 cols = 512 elements; each thread does 2
      for (int e = t; e < 512; e += 256) {
        int r = e >> 5, c = e & 31;
        if (r != p) M[r][c] -= dfac[r] * M[p][c];
      }
    }
    __syncthreads();
  }

  // gain[j][d] = sum_k Minv[j][k] * HC[d][k]   (Minv = M[:,16:32])
  for (int idx = t; idx < 2048; idx += 256) {
    int j = idx >> 7, dd = idx & 127;
    double acc = 0.0;
    for (int k = 0; k < 16; ++k) acc += M[j][16 + k] * (double)sHC[dd * 16 + k];
    float g = (float)acc;
    sgain[j * 128 + dd] = g;
    gain[j * 128 + dd] = g;
  }
  __syncthreads();

  if (t == 0) {
    float tr = 0.0f;
    for (int j = 0; j < 16; ++j) {
      float s2 = 0.0f;
      for (int dd = 0; dd < 128; ++dd) s2 += sgain[j * 128 + dd] * sHC[dd * 16 + j];
      tr += sC[j][j] - s2;
    }
    tr = fmaxf(tr, 0.0f) + 1e-6f;
    scal[0] = tr;
  }
}

// ---------------- Kernel 2: per-observation proposal concentrations ----------------
__global__ __launch_bounds__(256) void diri_kernel(const float* __restrict__ y,
                                                   char* __restrict__ ws) {
  float* m    = (float*)(ws + WS_M);
  float* EY   = (float*)(ws + WS_EY);
  float* gain = (float*)(ws + WS_GAIN);
  float* scal = (float*)(ws + WS_SCAL);
  float* diri = (float*)(ws + WS_DIRI);
  float* qc   = (float*)(ws + WS_QC);

  __shared__ float sg[16 * 128];
  __shared__ float sEY[128];
  __shared__ float sm[16];
  __shared__ float s_tr;

  int t = threadIdx.x;
  for (int i = t; i < 2048; i += 256) sg[i] = gain[i];
  if (t < 128) sEY[t] = EY[t];
  if (t < 16) sm[t] = m[t];
  if (t == 0) s_tr = scal[0];
  __syncthreads();

  int n = blockIdx.x * 256 + t;
  float tv[16];
  for (int j = 0; j < 16; ++j) tv[j] = sm[j];
  const float* yn = y + n * 128;
  for (int dd = 0; dd < 128; ++dd) {
    float dy = yn[dd] - sEY[dd];
    for (int j = 0; j < 16; ++j) tv[j] += dy * sg[j * 128 + dd];
  }
  float s = 0.0f;
  for (int j = 0; j < 16; ++j) { tv[j] = fmaxf(tv[j], 0.0f) + 1e-6f; s += tv[j]; }
  float ssq = 0.0f;
  for (int j = 0; j < 16; ++j) { tv[j] = tv[j] / s; ssq += tv[j] * tv[j]; }
  float k = (1.0f - ssq) / s_tr - 1.0f;
  float dsum = 0.0f, lgs = 0.0f;
  float* dn = diri + n * 16;
  for (int j = 0; j < 16; ++j) {
    float dj = fmaxf(k * tv[j], 0.0f) + 0.8f;
    dn[j] = dj; dsum += dj; lgs += lgammaf(dj);
  }
  qc[n] = lgammaf(dsum) - lgs;
}

// ---------------- Kernel 3: sampling + importance-weighted moments ----------------
__global__ __launch_bounds__(256) void main_kernel(const float* __restrict__ y,
                                                   const float* __restrict__ H,
                                                   const float* __restrict__ alpha,
                                                   const char* __restrict__ ws,
                                                   float* __restrict__ out) {
  const float* diri = (const float*)(ws + WS_DIRI);
  const float* qc   = (const float*)(ws + WS_QC);
  const float* scal = (const float*)(ws + WS_SCAL);

  __shared__ float sHt[16][128];     // H transposed: sHt[j][d]
  __shared__ float sy[128];
  __shared__ float sdiri[16], salpha[16];
  __shared__ float slg[16][16];
  __shared__ float sz[16][17];       // z samples for 16 h's (+pad)
  __shared__ float red_q[256], red_p[256], red_s[256];
  __shared__ float slw[16], swv[16];
  __shared__ float sM, sS, sFac, sqc, spc;

  int t = threadIdx.x;
  int n = blockIdx.x;
  int h_sub = t >> 4, j = t & 15;

  for (int i = t; i < 2048; i += 256) {
    int dd = i & 127, jj = i >> 7;
    sHt[jj][dd] = H[dd * 16 + jj];
  }
  if (t < 128) sy[t] = y[n * 128 + t];
  if (t < 16) { sdiri[t] = diri[n * 16 + t]; salpha[t] = alpha[t]; }
  if (t == 0) { sM = -INFINITY; sS = 0.0f; sFac = 1.0f; sqc = qc[n]; spc = scal[1]; }
  __syncthreads();

  float acc = 0.0f;     // zzy[k=h_sub][l=j]
  float zyacc = 0.0f;   // threads t<16 own zy[t]
  float dj1 = sdiri[j] - 1.0f;
  float aj1 = salpha[j] - 1.0f;

  for (int cch = 0; cch < 32; ++cch) {
    int h = cch * 16 + h_sub;
    bool valid = (h < NSAMP);
    float lg = 0.0f;
    if (valid) {
      uint32_t jf = (((uint32_t)h * 2048u + (uint32_t)n) << 4) | (uint32_t)j;
      lg = sample_loggamma(jf, sdiri[j]);
    }
    slg[h_sub][j] = lg;
    __syncthreads();

    // softmax over the 16 components of row h_sub
    float mx = -INFINITY;
    for (int jj = 0; jj < 16; ++jj) mx = fmaxf(mx, slg[h_sub][jj]);
    float se = 0.0f;
    for (int jj = 0; jj < 16; ++jj) se += fexp(slg[h_sub][jj] - mx);
    float z = valid ? (fexp(lg - mx) / se) : 0.0f;
    sz[h_sub][j] = z;
    float lz = flog(z);
    red_q[t] = dj1 * lz;
    red_p[t] = aj1 * lz;
    __syncthreads();

    // residual: thread covers d = j + 16*s, s=0..7
    float rs[8];
    for (int s8 = 0; s8 < 8; ++s8) rs[s8] = -sy[j + 16 * s8];
    for (int jj = 0; jj < 16; ++jj) {
      float zv = sz[h_sub][jj];
      for (int s8 = 0; s8 < 8; ++s8) rs[s8] += sHt[jj][j + 16 * s8] * zv;
    }
    float ss = 0.0f;
    for (int s8 = 0; s8 < 8; ++s8) ss += rs[s8] * rs[s8];
    red_s[t] = ss;
    __syncthreads();

    if (j == 0) {
      float q = 0.0f, p2 = 0.0f, s3 = 0.0f;
      for (int jj = 0; jj < 16; ++jj) {
        q  += red_q[h_sub * 16 + jj];
        p2 += red_p[h_sub * 16 + jj];
        s3 += red_s[h_sub * 16 + jj];
      }
      float pyz = s3 / (-0.02f);
      float lw = pyz + (p2 + spc) - (q + sqc);
      slw[h_sub] = valid ? lw : -INFINITY;
    }
    __syncthreads();

    if (t == 0) {
      float cmax = sM;
      for (int hh = 0; hh < 16; ++hh) cmax = fmaxf(cmax, slw[hh]);
      float f2 = fexp(sM - cmax);
      float Snew = sS * f2;
      for (int hh = 0; hh < 16; ++hh) {
        float w = fexp(slw[hh] - cmax);
        swv[hh] = w; Snew += w;
      }
      sM = cmax; sS = Snew; sFac = f2;
    }
    __syncthreads();

    float fc = sFac;
    float a2 = acc * fc;
    for (int hh = 0; hh < 16; ++hh) a2 += swv[hh] * sz[hh][h_sub] * sz[hh][j];
    acc = a2;
    if (t < 16) {
      float zv2 = zyacc * fc;
      for (int hh = 0; hh < 16; ++hh) zv2 += swv[hh] * sz[hh][t];
      zyacc = zv2;
    }
    __syncthreads();
  }

  float Sf = sS;
  if (t < 16) out[n * 16 + t] = zyacc / Sf;
  out[N_OBS * R_DIM + n * 256 + t] = acc / Sf;
}

extern "C" void kernel_launch(void* const* d_in, const int* in_sizes, int n_in,
                              void* d_out, int out_size, void* d_ws, size_t ws_size,
                              hipStream_t stream) {
  const float* y     = (const float*)d_in[0];
  const float* H     = (const float*)d_in[1];
  const float* alpha = (const float*)d_in[2];
  char* ws = (char*)d_ws;
  float* out = (float*)d_out;

  prep_kernel<<<1, 256, 0, stream>>>(H, alpha, ws);
  diri_kernel<<<8, 256, 0, stream>>>(y, ws);
  main_kernel<<<N_OBS, 256, 0, stream>>>(y, H, alpha, ws, out);
}

// Round 4
// 1043.750 us; speedup vs baseline: 6.0761x; 1.4229x over previous
//
#include <hip/hip_runtime.h>
#include <cstdint>
#include <cmath>

#pragma clang fp contract(off)

#define N_OBS 2048
#define D_DIM 128
#define R_DIM 16
#define NSAMP 500

// ---- workspace layout (bytes) ----
#define WS_M     0        // 16 f32
#define WS_EY    64       // 128 f32
#define WS_GAIN  576      // 16*128 f32
#define WS_SCAL  8768     // scalars: [0]=trace_C, [1]=pconst, [2]=alpha0
#define WS_DIRI  279136   // 2048*16 f32
#define WS_QC    410208   // 2048 f32

// ---- f32 transcendentals computed through double — used ONLY in the
// accept/reject-critical sampler path (flip boundaries must match reference).
__device__ __forceinline__ float flog(float x)   { return (float)log((double)x); }
__device__ __forceinline__ float flog1p(float x) { return (float)log1p((double)x); }

// ---------------- Threefry-2x32, 20 rounds (JAX-compatible) ----------------
__device__ __forceinline__ void tf_block(uint32_t k0, uint32_t k1,
                                         uint32_t x0, uint32_t x1,
                                         uint32_t& o0, uint32_t& o1) {
  const uint32_t k2 = k0 ^ k1 ^ 0x1BD11BDAu;
  x0 += k0; x1 += k1;
#define TF_R(r) { x0 += x1; x1 = (x1 << (r)) | (x1 >> (32 - (r))); x1 ^= x0; }
  TF_R(13) TF_R(15) TF_R(26) TF_R(6)
  x0 += k1; x1 += k2 + 1u;
  TF_R(17) TF_R(29) TF_R(16) TF_R(24)
  x0 += k2; x1 += k0 + 2u;
  TF_R(13) TF_R(15) TF_R(26) TF_R(6)
  x0 += k0; x1 += k1 + 3u;
  TF_R(17) TF_R(29) TF_R(16) TF_R(24)
  x0 += k1; x1 += k2 + 4u;
  TF_R(13) TF_R(15) TF_R(26) TF_R(6)
  x0 += k2; x1 += k0 + 5u;
#undef TF_R
  o0 = x0; o1 = x1;
}

// scalar random_bits under threefry_partitionable: block over count (0,0), xor halves
__device__ __forceinline__ uint32_t rb32(uint32_t ka, uint32_t kb) {
  uint32_t o0, o1;
  tf_block(ka, kb, 0u, 0u, o0, o1);
  return o0 ^ o1;
}

// JAX uniform [0,1): randomize mantissa with exponent 1, subtract 1
__device__ __forceinline__ float u01(uint32_t bits) {
  uint32_t fb = (bits >> 9) | 0x3F800000u;
  return __uint_as_float(fb) - 1.0f;
}

// XLA f32 ErfInv polynomial (Giles) — HLO-level expansion, identical on CPU/GPU
__device__ __forceinline__ float erfinv_xla(float x) {
  float w = -flog1p(-(x * x));
  float p;
  if (w < 5.0f) {
    w = w - 2.5f;
    p = 2.81022636e-08f;
    p = 3.43273939e-07f + p * w;
    p = -3.5233877e-06f + p * w;
    p = -4.39150654e-06f + p * w;
    p = 0.00021858087f + p * w;
    p = -0.00125372503f + p * w;
    p = -0.00417768164f + p * w;
    p = 0.246640727f + p * w;
    p = 1.50140941f + p * w;
  } else {
    w = sqrtf(w) - 3.0f;
    p = -0.000200214257f;
    p = 0.000100950558f + p * w;
    p = 0.00134934322f + p * w;
    p = -0.00367342844f + p * w;
    p = 0.00573950773f + p * w;
    p = -0.0076224613f + p * w;
    p = 0.00943887047f + p * w;
    p = 1.00167406f + p * w;
    p = 2.83297682f + p * w;
  }
  return p * x;
}

// normal(key) = sqrt(2)*erfinv(uniform(lo=-0.99999994, hi=1))
__device__ __forceinline__ float normal_jax(uint32_t ka, uint32_t kb) {
  float f = u01(rb32(ka, kb));
  float u = f * 2.0f + (-0.99999994f);
  u = fmaxf(-0.99999994f, u);
  return 1.41421356f * erfinv_xla(u);
}

// _gamma_one(key_j, a, log_space=True) with key_j = TF((0,42), 0, jf)  [foldlike split]
__device__ float sample_loggamma(uint32_t jf, float a) {
  uint32_t ka, kb;
  tf_block(0u, 42u, 0u, jf, ka, kb);     // per-sample key

  // key, subkey = split(key)   (foldlike: block counts (0,0) and (0,1))
  uint32_t k1a, k1b, ska, skb;
  tf_block(ka, kb, 0u, 0u, k1a, k1b);
  tf_block(ka, kb, 0u, 1u, ska, skb);

  // log_boost source = -Exponential(subkey) = log1p(-uniform(subkey))
  float ef = u01(rb32(ska, skb));
  float log_samples = flog1p(-ef);

  bool boost = (a >= 1.0f);
  float a_orig = a;
  float aa = boost ? a : (a + 1.0f);
  float d = aa - 0.33333334f;
  float c = 0.33333334f / sqrtf(d);

  uint32_t kcx = k1a, kcy = k1b;
  float X = 0.0f, V = 1.0f;
  for (int it = 0; it < 256; ++it) {
    uint32_t kna, knb, xka, xkb, Uka, Ukb;
    tf_block(kcx, kcy, 0u, 0u, kna, knb);   // new carry key
    tf_block(kcx, kcy, 0u, 1u, xka, xkb);   // x_key
    tf_block(kcx, kcy, 0u, 2u, Uka, Ukb);   // U_key
    kcx = kna; kcy = knb;
    float x = 0.0f, v = -1.0f;
    for (int in = 0; in < 256; ++in) {
      uint32_t nxa, nxb, sxa, sxb;
      tf_block(xka, xkb, 0u, 0u, nxa, nxb); // carried x_key
      tf_block(xka, xkb, 0u, 1u, sxa, sxb); // subkey for normal
      xka = nxa; xkb = nxb;
      x = normal_jax(sxa, sxb);
      v = 1.0f + x * c;
      if (v > 0.0f) break;
    }
    X = x * x;
    V = (v * v) * v;
    float U = u01(rb32(Uka, Ukb));
    // continue while BOTH hold; accept (break) when either fails.
    bool cond = (U >= 1.0f - 0.0331f * (X * X)) &&
                (flog(U) >= X * 0.5f + d * ((1.0f - V) + flog(V)));
    if (!cond) break;
  }
  float log_boost = (boost || log_samples == 0.0f) ? 0.0f
                                                   : log_samples * (1.0f / a_orig);
  return (flog(d) + flog(V)) + log_boost;
}

// ---------------- Kernel 1: LMMSE prep (1 block, Woodbury 16x16) ----------------
// gain = C H^T (sI + H C H^T)^-1  ==  (sI16 + C H^T H)^-1 C H^T   [push-through]
__global__ __launch_bounds__(256) void prep_kernel(const float* __restrict__ H,
                                                   const float* __restrict__ alpha,
                                                   char* __restrict__ ws) {
  float* m    = (float*)(ws + WS_M);
  float* EY   = (float*)(ws + WS_EY);
  float* gain = (float*)(ws + WS_GAIN);
  float* scal = (float*)(ws + WS_SCAL);

  __shared__ float sH[128 * 16];
  __shared__ float sC[16][16];
  __shared__ float sHC[128 * 16];    // (H C)[d][j], f32 to match reference path
  __shared__ float sm[16];
  __shared__ double sHtH[16][16];
  __shared__ double M[16][33];       // augmented [M | I], 32 cols + pad
  __shared__ double dfac[16];
  __shared__ double spiv;
  __shared__ int   spivrow;
  __shared__ float sgain[16 * 128];

  int t = threadIdx.x;
  for (int i = t; i < 2048; i += 256) sH[i] = H[i];
  __syncthreads();

  if (t == 0) {
    float a0 = 0.0f;
    for (int j = 0; j < 16; ++j) a0 += alpha[j];
    float pc = lgammaf(a0);
    for (int j = 0; j < 16; ++j) pc -= lgammaf(alpha[j]);
    scal[2] = a0; scal[1] = pc;
    for (int j = 0; j < 16; ++j) { sm[j] = alpha[j] / a0; m[j] = sm[j]; }
  }
  __syncthreads();
  float a0 = scal[2];

  {
    int i = t >> 4, j = t & 15;
    float v = ((i == j) ? sm[i] : 0.0f) - sm[i] * sm[j];
    sC[i][j] = v / (a0 + 1.0f);
  }
  if (t < 128) {
    float acc = 0.0f;
    for (int j = 0; j < 16; ++j) acc += sH[t * 16 + j] * sm[j];
    EY[t] = acc;
  }
  __syncthreads();

  // HC[d][j] = sum_i H[d][i] C[i][j]  (f32)
  for (int idx = t; idx < 2048; idx += 256) {
    int dd = idx >> 4, j = idx & 15;
    float acc = 0.0f;
    for (int i = 0; i < 16; ++i) acc += sH[dd * 16 + i] * sC[i][j];
    sHC[idx] = acc;
  }
  // HtH[i][j] = sum_d H[d][i] H[d][j]  (f64)
  {
    int i = t >> 4, j = t & 15;
    double acc = 0.0;
    for (int dd = 0; dd < 128; ++dd)
      acc += (double)sH[dd * 16 + i] * (double)sH[dd * 16 + j];
    sHtH[i][j] = acc;
  }
  __syncthreads();

  // M = sigma*I + C * HtH  (f64), augmented with I
  {
    int i = t >> 4, j = t & 15;
    double acc = (i == j) ? 0.01 : 0.0;
    for (int k = 0; k < 16; ++k) acc += (double)sC[i][k] * sHtH[k][j];
    M[i][j] = acc;
    M[i][16 + j] = (i == j) ? 1.0 : 0.0;
  }
  __syncthreads();

  // Gauss-Jordan with partial pivoting on 16x32 (f64, all-LDS)
  for (int p = 0; p < 16; ++p) {
    if (t == 0) {
      int best = p; double bv = fabs(M[p][p]);
      for (int r = p + 1; r < 16; ++r) {
        double v = fabs(M[r][p]);
        if (v > bv) { bv = v; best = r; }
      }
      spivrow = best;
    }
    __syncthreads();
    int pr = spivrow;
    double va = 0.0, vb = 0.0;
    if (t < 32 && pr != p) { va = M[p][t]; vb = M[pr][t]; }
    __syncthreads();
    if (t < 32 && pr != p) { M[p][t] = vb; M[pr][t] = va; }
    __syncthreads();
    if (t == 0) spiv = 1.0 / M[p][p];
    __syncthreads();
    if (t < 32) M[p][t] *= spiv;
    if (t < 16) dfac[t] = M[t][p];
    __syncthreads();
    {
      for (int e = t; e < 512; e += 256) {
        int r = e >> 5, c = e & 31;
        if (r != p) M[r][c] -= dfac[r] * M[p][c];
      }
    }
    __syncthreads();
  }

  // gain[j][d] = sum_k Minv[j][k] * HC[d][k]   (Minv = M[:,16:32])
  for (int idx = t; idx < 2048; idx += 256) {
    int j = idx >> 7, dd = idx & 127;
    double acc = 0.0;
    for (int k = 0; k < 16; ++k) acc += M[j][16 + k] * (double)sHC[dd * 16 + k];
    float g = (float)acc;
    sgain[j * 128 + dd] = g;
    gain[j * 128 + dd] = g;
  }
  __syncthreads();

  if (t == 0) {
    float tr = 0.0f;
    for (int j = 0; j < 16; ++j) {
      float s2 = 0.0f;
      for (int dd = 0; dd < 128; ++dd) s2 += sgain[j * 128 + dd] * sHC[dd * 16 + j];
      tr += sC[j][j] - s2;
    }
    tr = fmaxf(tr, 0.0f) + 1e-6f;
    scal[0] = tr;
  }
}

// ---------------- Kernel 2: per-observation proposal concentrations ----------------
__global__ __launch_bounds__(256) void diri_kernel(const float* __restrict__ y,
                                                   char* __restrict__ ws) {
  float* m    = (float*)(ws + WS_M);
  float* EY   = (float*)(ws + WS_EY);
  float* gain = (float*)(ws + WS_GAIN);
  float* scal = (float*)(ws + WS_SCAL);
  float* diri = (float*)(ws + WS_DIRI);
  float* qc   = (float*)(ws + WS_QC);

  __shared__ float sg[16 * 128];
  __shared__ float sEY[128];
  __shared__ float sm[16];
  __shared__ float s_tr;

  int t = threadIdx.x;
  for (int i = t; i < 2048; i += 256) sg[i] = gain[i];
  if (t < 128) sEY[t] = EY[t];
  if (t < 16) sm[t] = m[t];
  if (t == 0) s_tr = scal[0];
  __syncthreads();

  int n = blockIdx.x * 256 + t;
  float tv[16];
  for (int j = 0; j < 16; ++j) tv[j] = sm[j];
  const float* yn = y + n * 128;
  for (int dd = 0; dd < 128; ++dd) {
    float dy = yn[dd] - sEY[dd];
    for (int j = 0; j < 16; ++j) tv[j] += dy * sg[j * 128 + dd];
  }
  float s = 0.0f;
  for (int j = 0; j < 16; ++j) { tv[j] = fmaxf(tv[j], 0.0f) + 1e-6f; s += tv[j]; }
  float ssq = 0.0f;
  for (int j = 0; j < 16; ++j) { tv[j] = tv[j] / s; ssq += tv[j] * tv[j]; }
  float k = (1.0f - ssq) / s_tr - 1.0f;
  float dsum = 0.0f, lgs = 0.0f;
  float* dn = diri + n * 16;
  for (int j = 0; j < 16; ++j) {
    float dj = fmaxf(k * tv[j], 0.0f) + 0.8f;
    dn[j] = dj; dsum += dj; lgs += lgammaf(dj);
  }
  qc[n] = lgammaf(dsum) - lgs;
}

// ---------------- Kernel 3: sampling + importance-weighted moments ----------------
// Weight/softmax path is continuous (no accept/reject) -> f32 expf/logf, deduped.
// Row-local LDS traffic (16 contiguous lanes = one wave segment) relies on
// intra-wave LDS ordering; only cross-wave data (slw, swv, sz, sFac) gets barriers.
__global__ __launch_bounds__(256) void main_kernel(const float* __restrict__ y,
                                                   const float* __restrict__ H,
                                                   const float* __restrict__ alpha,
                                                   const char* __restrict__ ws,
                                                   float* __restrict__ out) {
  const float* diri = (const float*)(ws + WS_DIRI);
  const float* qc   = (const float*)(ws + WS_QC);
  const float* scal = (const float*)(ws + WS_SCAL);

  __shared__ float sHt[16][128];     // H transposed: sHt[j][d]
  __shared__ float sy[128];
  __shared__ float sdiri[16], salpha[16];
  __shared__ float slg[16][17];
  __shared__ float sez[16][17];
  __shared__ float sz[16][17];       // z samples for 16 h's (+pad)
  __shared__ float red_q[256], red_p[256], red_s[256];
  __shared__ float slw[16], swv[16];
  __shared__ float sM, sS, sFac, sqc, spc;

  int t = threadIdx.x;
  int n = blockIdx.x;
  int h_sub = t >> 4, j = t & 15;

  for (int i = t; i < 2048; i += 256) {
    int dd = i & 127, jj = i >> 7;
    sHt[jj][dd] = H[dd * 16 + jj];
  }
  if (t < 128) sy[t] = y[n * 128 + t];
  if (t < 16) { sdiri[t] = diri[n * 16 + t]; salpha[t] = alpha[t]; }
  if (t == 0) { sM = -INFINITY; sS = 0.0f; sFac = 1.0f; sqc = qc[n]; spc = scal[1]; }
  __syncthreads();

  float acc = 0.0f;     // zzy[k=h_sub][l=j]
  float zyacc = 0.0f;   // threads t<16 own zy[t]
  float dj1 = sdiri[j] - 1.0f;
  float aj1 = salpha[j] - 1.0f;

  for (int cch = 0; cch < 32; ++cch) {
    int h = cch * 16 + h_sub;
    bool valid = (h < NSAMP);
    float lg = 0.0f;
    if (valid) {
      uint32_t jf = (((uint32_t)h * 2048u + (uint32_t)n) << 4) | (uint32_t)j;
      lg = sample_loggamma(jf, sdiri[j]);
    }
    slg[h_sub][j] = lg;

    // ---- row-local softmax (16 lanes of a row are in one wave) ----
    float mx = -INFINITY;
    for (int jj = 0; jj < 16; ++jj) mx = fmaxf(mx, slg[h_sub][jj]);
    float ez = expf(lg - mx);          // ONE exp per thread (was 17)
    sez[h_sub][j] = ez;
    float se = 0.0f;
    for (int jj = 0; jj < 16; ++jj) se += sez[h_sub][jj];
    float z = valid ? (ez / se) : 0.0f;
    sz[h_sub][j] = z;
    float lz = logf(z);
    red_q[t] = dj1 * lz;
    red_p[t] = aj1 * lz;

    // residual: thread covers d = j + 16*s, s=0..7 (reads own row of sz)
    float rs[8];
    for (int s8 = 0; s8 < 8; ++s8) rs[s8] = -sy[j + 16 * s8];
    for (int jj = 0; jj < 16; ++jj) {
      float zv = sz[h_sub][jj];
      for (int s8 = 0; s8 < 8; ++s8) rs[s8] += sHt[jj][j + 16 * s8] * zv;
    }
    float ss = 0.0f;
    for (int s8 = 0; s8 < 8; ++s8) ss += rs[s8] * rs[s8];
    red_s[t] = ss;

    if (j == 0) {
      float q = 0.0f, p2 = 0.0f, s3 = 0.0f;
      for (int jj = 0; jj < 16; ++jj) {
        q  += red_q[h_sub * 16 + jj];
        p2 += red_p[h_sub * 16 + jj];
        s3 += red_s[h_sub * 16 + jj];
      }
      float pyz = s3 / (-0.02f);
      float lw = pyz + (p2 + spc) - (q + sqc);
      slw[h_sub] = valid ? lw : -INFINITY;
    }
    __syncthreads();   // B1: slw + all rows' sz visible

    if (t < 16) {
      float cmax = sM;
      for (int hh = 0; hh < 16; ++hh) cmax = fmaxf(cmax, slw[hh]);
      float w = expf(slw[t] - cmax);   // parallel across 16 lanes (was serial x17)
      swv[t] = w;
      if (t == 0) {
        float f2 = expf(sM - cmax);
        float Snew = sS * f2;
        for (int hh = 0; hh < 16; ++hh) Snew += swv[hh];  // same-wave LDS, ordered
        sM = cmax; sS = Snew; sFac = f2;
      }
    }
    __syncthreads();   // B2: swv, sFac visible

    float fc = sFac;
    float a2 = acc * fc;
    for (int hh = 0; hh < 16; ++hh) a2 += swv[hh] * sz[hh][h_sub] * sz[hh][j];
    acc = a2;
    if (t < 16) {
      float zv2 = zyacc * fc;
      for (int hh = 0; hh < 16; ++hh) zv2 += swv[hh] * sz[hh][t];
      zyacc = zv2;
    }
    __syncthreads();   // B3: protect sz/slg/red from next chunk's overwrite
  }

  float Sf = sS;
  if (t < 16) out[n * 16 + t] = zyacc / Sf;
  out[N_OBS * R_DIM + n * 256 + t] = acc / Sf;
}

extern "C" void kernel_launch(void* const* d_in, const int* in_sizes, int n_in,
                              void* d_out, int out_size, void* d_ws, size_t ws_size,
                              hipStream_t stream) {
  const float* y     = (const float*)d_in[0];
  const float* H     = (const float*)d_in[1];
  const float* alpha = (const float*)d_in[2];
  char* ws = (char*)d_ws;
  float* out = (float*)d_out;

  prep_kernel<<<1, 256, 0, stream>>>(H, alpha, ws);
  diri_kernel<<<8, 256, 0, stream>>>(y, ws);
  main_kernel<<<N_OBS, 256, 0, stream>>>(y, H, alpha, ws, out);
}

// Round 5
// 836.967 us; speedup vs baseline: 7.5772x; 1.2471x over previous
//
#include <hip/hip_runtime.h>
#include <cstdint>
#include <cmath>

#pragma clang fp contract(off)

#define N_OBS 2048
#define D_DIM 128
#define R_DIM 16
#define NSAMP 500

// ---- workspace layout (bytes) ----
#define WS_M     0        // 16 f32
#define WS_EY    64       // 128 f32
#define WS_GAIN  576      // 16*128 f32
#define WS_SCAL  8768     // scalars: [0]=trace_C, [1]=pconst, [2]=alpha0
#define WS_G     8800     // 16*16 f32  G = H^T H
#define WS_DIRI  279136   // 2048*16 f32
#define WS_QC    410208   // 2048 f32: folded const c_n = spc - qc_n - 50*||y_n||^2
#define WS_U     418400   // 2048*16 f32: u_n = H^T y_n

// ---- f64-path f32 transcendentals: ONLY for accept/reject-critical values
// (normal draw via erfinv, and the acceptance log-test). Matching glibc/XLA-CPU
// rounding here is what keeps the rejection stream aligned (round-2 lesson).
__device__ __forceinline__ float flog(float x)   { return (float)log((double)x); }
__device__ __forceinline__ float flog1p(float x) { return (float)log1p((double)x); }

// ---------------- Threefry-2x32, 20 rounds (JAX-compatible) ----------------
__device__ __forceinline__ void tf_block(uint32_t k0, uint32_t k1,
                                         uint32_t x0, uint32_t x1,
                                         uint32_t& o0, uint32_t& o1) {
  const uint32_t k2 = k0 ^ k1 ^ 0x1BD11BDAu;
  x0 += k0; x1 += k1;
#define TF_R(r) { x0 += x1; x1 = (x1 << (r)) | (x1 >> (32 - (r))); x1 ^= x0; }
  TF_R(13) TF_R(15) TF_R(26) TF_R(6)
  x0 += k1; x1 += k2 + 1u;
  TF_R(17) TF_R(29) TF_R(16) TF_R(24)
  x0 += k2; x1 += k0 + 2u;
  TF_R(13) TF_R(15) TF_R(26) TF_R(6)
  x0 += k0; x1 += k1 + 3u;
  TF_R(17) TF_R(29) TF_R(16) TF_R(24)
  x0 += k1; x1 += k2 + 4u;
  TF_R(13) TF_R(15) TF_R(26) TF_R(6)
  x0 += k2; x1 += k0 + 5u;
#undef TF_R
  o0 = x0; o1 = x1;
}

__device__ __forceinline__ uint32_t rb32(uint32_t ka, uint32_t kb) {
  uint32_t o0, o1;
  tf_block(ka, kb, 0u, 0u, o0, o1);
  return o0 ^ o1;
}

__device__ __forceinline__ float u01(uint32_t bits) {
  uint32_t fb = (bits >> 9) | 0x3F800000u;
  return __uint_as_float(fb) - 1.0f;
}

// XLA f32 ErfInv polynomial (Giles); feeds the normal draw -> accept/reject critical
__device__ __forceinline__ float erfinv_xla(float x) {
  float w = -flog1p(-(x * x));
  float p;
  if (w < 5.0f) {
    w = w - 2.5f;
    p = 2.81022636e-08f;
    p = 3.43273939e-07f + p * w;
    p = -3.5233877e-06f + p * w;
    p = -4.39150654e-06f + p * w;
    p = 0.00021858087f + p * w;
    p = -0.00125372503f + p * w;
    p = -0.00417768164f + p * w;
    p = 0.246640727f + p * w;
    p = 1.50140941f + p * w;
  } else {
    w = sqrtf(w) - 3.0f;
    p = -0.000200214257f;
    p = 0.000100950558f + p * w;
    p = 0.00134934322f + p * w;
    p = -0.00367342844f + p * w;
    p = 0.00573950773f + p * w;
    p = -0.0076224613f + p * w;
    p = 0.00943887047f + p * w;
    p = 1.00167406f + p * w;
    p = 2.83297682f + p * w;
  }
  return p * x;
}

__device__ __forceinline__ float normal_jax(uint32_t ka, uint32_t kb) {
  float f = u01(rb32(ka, kb));
  float u = f * 2.0f + (-0.99999994f);
  u = fmaxf(-0.99999994f, u);
  return 1.41421356f * erfinv_xla(u);
}

// _gamma_one(key_j, a, log_space=True); carry keys computed lazily (only on
// actual loop repeat) — identical Threefry stream, fewer blocks on accept path.
__device__ float sample_loggamma(uint32_t jf, float a) {
  uint32_t ka, kb;
  tf_block(0u, 42u, 0u, jf, ka, kb);     // per-sample key (foldlike split)

  uint32_t k1a, k1b, ska, skb;
  tf_block(ka, kb, 0u, 0u, k1a, k1b);    // carried key
  tf_block(ka, kb, 0u, 1u, ska, skb);    // subkey -> exponential

  float ef = u01(rb32(ska, skb));
  float log_samples = log1pf(-ef);       // continuous (boost value) -> f32

  bool boost = (a >= 1.0f);
  float a_orig = a;
  float aa = boost ? a : (a + 1.0f);
  float d = aa - 0.33333334f;
  float c = 0.33333334f / sqrtf(d);

  uint32_t kcx = k1a, kcy = k1b;
  float V = 1.0f;
  for (int it = 0; it < 256; ++it) {
    uint32_t xka, xkb, Uka, Ukb;
    tf_block(kcx, kcy, 0u, 1u, xka, xkb);   // x_key
    tf_block(kcx, kcy, 0u, 2u, Uka, Ukb);   // U_key
    float x = 0.0f, v = -1.0f;
    for (int in = 0; in < 256; ++in) {
      uint32_t sxa, sxb;
      tf_block(xka, xkb, 0u, 1u, sxa, sxb); // subkey for normal (from OLD x_key)
      x = normal_jax(sxa, sxb);
      v = 1.0f + x * c;
      if (v > 0.0f) break;
      uint32_t nxa, nxb;
      tf_block(xka, xkb, 0u, 0u, nxa, nxb); // lazy inner carry
      xka = nxa; xkb = nxb;
    }
    float X = x * x;
    V = (v * v) * v;
    float U = u01(rb32(Uka, Ukb));
    // continue while BOTH hold; accept (break) when either fails.
    bool cont = (U >= 1.0f - 0.0331f * (X * X));
    if (cont) cont = (flog(U) >= X * 0.5f + d * ((1.0f - V) + flog(V)));
    if (!cont) break;
    uint32_t kna, knb;
    tf_block(kcx, kcy, 0u, 0u, kna, knb);   // lazy outer carry
    kcx = kna; kcy = knb;
  }
  float log_boost = (boost || log_samples == 0.0f) ? 0.0f
                                                   : log_samples * (1.0f / a_orig);
  return (logf(d) + logf(V)) + log_boost;   // continuous output value -> f32
}

// ---------------- Kernel 1: LMMSE prep (1 block, Woodbury 16x16) ----------------
__global__ __launch_bounds__(256) void prep_kernel(const float* __restrict__ H,
                                                   const float* __restrict__ alpha,
                                                   char* __restrict__ ws) {
  float* m    = (float*)(ws + WS_M);
  float* EY   = (float*)(ws + WS_EY);
  float* gain = (float*)(ws + WS_GAIN);
  float* scal = (float*)(ws + WS_SCAL);
  float* Gws  = (float*)(ws + WS_G);

  __shared__ float sH[128 * 16];
  __shared__ float sC[16][16];
  __shared__ float sHC[128 * 16];
  __shared__ float sm[16];
  __shared__ double sHtH[16][16];
  __shared__ double M[16][33];
  __shared__ double dfac[16];
  __shared__ double spiv;
  __shared__ int   spivrow;
  __shared__ float sgain[16 * 128];

  int t = threadIdx.x;
  for (int i = t; i < 2048; i += 256) sH[i] = H[i];
  __syncthreads();

  if (t == 0) {
    float a0 = 0.0f;
    for (int j = 0; j < 16; ++j) a0 += alpha[j];
    float pc = lgammaf(a0);
    for (int j = 0; j < 16; ++j) pc -= lgammaf(alpha[j]);
    scal[2] = a0; scal[1] = pc;
    for (int j = 0; j < 16; ++j) { sm[j] = alpha[j] / a0; m[j] = sm[j]; }
  }
  __syncthreads();
  float a0 = scal[2];

  {
    int i = t >> 4, j = t & 15;
    float v = ((i == j) ? sm[i] : 0.0f) - sm[i] * sm[j];
    sC[i][j] = v / (a0 + 1.0f);
  }
  if (t < 128) {
    float acc = 0.0f;
    for (int j = 0; j < 16; ++j) acc += sH[t * 16 + j] * sm[j];
    EY[t] = acc;
  }
  __syncthreads();

  for (int idx = t; idx < 2048; idx += 256) {
    int dd = idx >> 4, j = idx & 15;
    float acc = 0.0f;
    for (int i = 0; i < 16; ++i) acc += sH[dd * 16 + i] * sC[i][j];
    sHC[idx] = acc;
  }
  {
    int i = t >> 4, j = t & 15;
    double acc = 0.0;
    for (int dd = 0; dd < 128; ++dd)
      acc += (double)sH[dd * 16 + i] * (double)sH[dd * 16 + j];
    sHtH[i][j] = acc;
    Gws[i * 16 + j] = (float)acc;     // G for the main-kernel quadratic form
  }
  __syncthreads();

  {
    int i = t >> 4, j = t & 15;
    double acc = (i == j) ? 0.01 : 0.0;
    for (int k = 0; k < 16; ++k) acc += (double)sC[i][k] * sHtH[k][j];
    M[i][j] = acc;
    M[i][16 + j] = (i == j) ? 1.0 : 0.0;
  }
  __syncthreads();

  for (int p = 0; p < 16; ++p) {
    if (t == 0) {
      int best = p; double bv = fabs(M[p][p]);
      for (int r = p + 1; r < 16; ++r) {
        double v = fabs(M[r][p]);
        if (v > bv) { bv = v; best = r; }
      }
      spivrow = best;
    }
    __syncthreads();
    int pr = spivrow;
    double va = 0.0, vb = 0.0;
    if (t < 32 && pr != p) { va = M[p][t]; vb = M[pr][t]; }
    __syncthreads();
    if (t < 32 && pr != p) { M[p][t] = vb; M[pr][t] = va; }
    __syncthreads();
    if (t == 0) spiv = 1.0 / M[p][p];
    __syncthreads();
    if (t < 32) M[p][t] *= spiv;
    if (t < 16) dfac[t] = M[t][p];
    __syncthreads();
    for (int e = t; e < 512; e += 256) {
      int r = e >> 5, c = e & 31;
      if (r != p) M[r][c] -= dfac[r] * M[p][c];
    }
    __syncthreads();
  }

  for (int idx = t; idx < 2048; idx += 256) {
    int j = idx >> 7, dd = idx & 127;
    double acc = 0.0;
    for (int k = 0; k < 16; ++k) acc += M[j][16 + k] * (double)sHC[dd * 16 + k];
    float g = (float)acc;
    sgain[j * 128 + dd] = g;
    gain[j * 128 + dd] = g;
  }
  __syncthreads();

  if (t == 0) {
    float tr = 0.0f;
    for (int j = 0; j < 16; ++j) {
      float s2 = 0.0f;
      for (int dd = 0; dd < 128; ++dd) s2 += sgain[j * 128 + dd] * sHC[dd * 16 + j];
      tr += sC[j][j] - s2;
    }
    tr = fmaxf(tr, 0.0f) + 1e-6f;
    scal[0] = tr;
  }
}

// ---------------- Kernel 2: per-n concentrations + u_n = H^T y_n + folded const ----------------
__global__ __launch_bounds__(256) void diri_kernel(const float* __restrict__ y,
                                                   const float* __restrict__ H,
                                                   char* __restrict__ ws) {
  float* m    = (float*)(ws + WS_M);
  float* EY   = (float*)(ws + WS_EY);
  float* gain = (float*)(ws + WS_GAIN);
  float* scal = (float*)(ws + WS_SCAL);
  float* diri = (float*)(ws + WS_DIRI);
  float* cns  = (float*)(ws + WS_QC);
  float* Uws  = (float*)(ws + WS_U);

  __shared__ float sg[16 * 128];
  __shared__ float sH[128 * 16];
  __shared__ float sEY[128];
  __shared__ float sm[16];
  __shared__ float s_tr, s_pc;

  int t = threadIdx.x;
  for (int i = t; i < 2048; i += 256) { sg[i] = gain[i]; sH[i] = H[i]; }
  if (t < 128) sEY[t] = EY[t];
  if (t < 16) sm[t] = m[t];
  if (t == 0) { s_tr = scal[0]; s_pc = scal[1]; }
  __syncthreads();

  int n = blockIdx.x * 256 + t;
  float tv[16], u[16];
#pragma unroll
  for (int j = 0; j < 16; ++j) { tv[j] = sm[j]; u[j] = 0.0f; }
  float yy = 0.0f;
  const float* yn = y + n * 128;
  for (int dd = 0; dd < 128; ++dd) {
    float yv = yn[dd];
    float dy = yv - sEY[dd];
    yy += yv * yv;
#pragma unroll
    for (int j = 0; j < 16; ++j) {
      tv[j] += dy * sg[j * 128 + dd];
      u[j]  += yv * sH[dd * 16 + j];
    }
  }
  float s = 0.0f;
#pragma unroll
  for (int j = 0; j < 16; ++j) { tv[j] = fmaxf(tv[j], 0.0f) + 1e-6f; s += tv[j]; }
  float ssq = 0.0f;
#pragma unroll
  for (int j = 0; j < 16; ++j) { tv[j] = tv[j] / s; ssq += tv[j] * tv[j]; }
  float k = (1.0f - ssq) / s_tr - 1.0f;
  float dsum = 0.0f, lgs = 0.0f;
  float* dn = diri + n * 16;
#pragma unroll
  for (int j = 0; j < 16; ++j) {
    float dj = fmaxf(k * tv[j], 0.0f) + 0.8f;
    dn[j] = dj; dsum += dj; lgs += lgammaf(dj);
    Uws[n * 16 + j] = u[j];
  }
  float qcn = lgammaf(dsum) - lgs;
  cns[n] = s_pc - qcn - 50.0f * yy;     // lw = -50*(zGz-2zu) + p2 - q + cn
}

// ---------------- Kernel 3: sampling + importance-weighted moments ----------------
// Residual via quadratic form zGz - 2zu (G rows in registers); row-local
// reductions via shfl_xor(width=16); only cross-wave state uses barriers.
__global__ __launch_bounds__(256) void main_kernel(const float* __restrict__ alpha,
                                                   const char* __restrict__ ws,
                                                   float* __restrict__ out) {
  const float* diri = (const float*)(ws + WS_DIRI);
  const float* cns  = (const float*)(ws + WS_QC);
  const float* Uw   = (const float*)(ws + WS_U);
  const float* Gw   = (const float*)(ws + WS_G);

  __shared__ float sz[16][17];
  __shared__ float slw[16], swv[16];
  __shared__ float sM, sS, sFac;

  int t = threadIdx.x;
  int n = blockIdx.x;
  int h_sub = t >> 4, j = t & 15;

  float Greg[16];
#pragma unroll
  for (int k = 0; k < 16; ++k) Greg[k] = Gw[j * 16 + k];
  float uj2 = 2.0f * Uw[n * 16 + j];
  float cn  = cns[n];
  float aj  = diri[n * 16 + j];
  float dj1 = aj - 1.0f;
  float aj1 = alpha[j] - 1.0f;
  if (t == 0) { sM = -INFINITY; sS = 0.0f; sFac = 1.0f; }
  __syncthreads();

  float acc = 0.0f;     // zzy[k=h_sub][l=j]
  float zyacc = 0.0f;   // threads t<16 own zy[t]

  for (int cch = 0; cch < 32; ++cch) {
    int h = cch * 16 + h_sub;
    bool valid = (h < NSAMP);
    float lg = 0.0f;
    if (valid) {
      uint32_t jf = (((uint32_t)h * 2048u + (uint32_t)n) << 4) | (uint32_t)j;
      lg = sample_loggamma(jf, aj);
    }

    // row softmax via intra-wave shuffles (row = 16 contiguous lanes)
    float mx = lg;
    mx = fmaxf(mx, __shfl_xor(mx, 1, 16));
    mx = fmaxf(mx, __shfl_xor(mx, 2, 16));
    mx = fmaxf(mx, __shfl_xor(mx, 4, 16));
    mx = fmaxf(mx, __shfl_xor(mx, 8, 16));
    float ez = expf(lg - mx);
    float se = ez;
    se += __shfl_xor(se, 1, 16);
    se += __shfl_xor(se, 2, 16);
    se += __shfl_xor(se, 4, 16);
    se += __shfl_xor(se, 8, 16);
    float z = valid ? (ez / se) : 0.0f;
    sz[h_sub][j] = z;                      // same-wave readers below
    float lz = logf(z);
    float q  = dj1 * lz;
    float p2 = aj1 * lz;

    // quadratic form: (Gz)_j then z_j*((Gz)_j - 2u_j); sz row reads are broadcast
    float gz = 0.0f;
#pragma unroll
    for (int k = 0; k < 16; ++k) gz = fmaf(Greg[k], sz[h_sub][k], gz);
    float sres = z * (gz - uj2);

    q    += __shfl_xor(q, 1, 16);
    q    += __shfl_xor(q, 2, 16);
    q    += __shfl_xor(q, 4, 16);
    q    += __shfl_xor(q, 8, 16);
    p2   += __shfl_xor(p2, 1, 16);
    p2   += __shfl_xor(p2, 2, 16);
    p2   += __shfl_xor(p2, 4, 16);
    p2   += __shfl_xor(p2, 8, 16);
    sres += __shfl_xor(sres, 1, 16);
    sres += __shfl_xor(sres, 2, 16);
    sres += __shfl_xor(sres, 4, 16);
    sres += __shfl_xor(sres, 8, 16);

    if (j == 0) {
      float lw = -50.0f * sres + p2 - q + cn;
      slw[h_sub] = valid ? lw : -INFINITY;
    }
    __syncthreads();   // B1: slw + all rows' sz visible

    if (t < 16) {
      float cmax = sM;
      for (int hh = 0; hh < 16; ++hh) cmax = fmaxf(cmax, slw[hh]);
      float w = expf(slw[t] - cmax);
      swv[t] = w;
      if (t == 0) {
        float f2 = expf(sM - cmax);
        float Snew = sS * f2;
        for (int hh = 0; hh < 16; ++hh) Snew += swv[hh];
        sM = cmax; sS = Snew; sFac = f2;
      }
    }
    __syncthreads();   // B2: swv, sFac visible

    float fc = sFac;
    acc *= fc;
#pragma unroll
    for (int hh = 0; hh < 16; ++hh)
      acc = fmaf(swv[hh] * sz[hh][h_sub], sz[hh][j], acc);
    if (t < 16) {
      zyacc *= fc;
#pragma unroll
      for (int hh = 0; hh < 16; ++hh) zyacc = fmaf(swv[hh], sz[hh][t], zyacc);
    }
    __syncthreads();   // B3: protect sz from next chunk's overwrite
  }

  float Sf = sS;
  if (t < 16) out[n * 16 + t] = zyacc / Sf;
  out[N_OBS * R_DIM + n * 256 + t] = acc / Sf;
}

extern "C" void kernel_launch(void* const* d_in, const int* in_sizes, int n_in,
                              void* d_out, int out_size, void* d_ws, size_t ws_size,
                              hipStream_t stream) {
  const float* y     = (const float*)d_in[0];
  const float* H     = (const float*)d_in[1];
  const float* alpha = (const float*)d_in[2];
  char* ws = (char*)d_ws;
  float* out = (float*)d_out;

  prep_kernel<<<1, 256, 0, stream>>>(H, alpha, ws);
  diri_kernel<<<8, 256, 0, stream>>>(y, H, ws);
  main_kernel<<<N_OBS, 256, 0, stream>>>(alpha, ws, out);
}

// Round 6
// 699.759 us; speedup vs baseline: 9.0630x; 1.1961x over previous
//
#include <hip/hip_runtime.h>
#include <cstdint>
#include <cmath>

#pragma clang fp contract(off)

#define N_OBS 2048
#define D_DIM 128
#define R_DIM 16
#define NSAMP 500

// ---- workspace layout (bytes) ----
#define WS_M     0        // 16 f32
#define WS_EY    64       // 128 f32
#define WS_GAIN  576      // 16*128 f32
#define WS_SCAL  8768     // scalars: [0]=trace_C, [1]=pconst, [2]=alpha0
#define WS_G     8800     // 16*16 f32  G = H^T H
#define WS_DIRI  279136   // 2048*16 f32
#define WS_QC    410208   // 2048 f32: folded const c_n = spc - qc_n - 50*||y_n||^2
#define WS_U     418400   // 2048*16 f32: u_n = H^T y_n

// ---- f64-path f32 transcendentals: ONLY for accept/reject-critical values
// (normal draw via erfinv, and the acceptance log-test). Matching glibc/XLA-CPU
// rounding here is what keeps the rejection stream aligned (round-2 lesson).
__device__ __forceinline__ float flog(float x)   { return (float)log((double)x); }
__device__ __forceinline__ float flog1p(float x) { return (float)log1p((double)x); }

// ---------------- Threefry-2x32, 20 rounds (JAX-compatible) ----------------
__device__ __forceinline__ void tf_block(uint32_t k0, uint32_t k1,
                                         uint32_t x0, uint32_t x1,
                                         uint32_t& o0, uint32_t& o1) {
  const uint32_t k2 = k0 ^ k1 ^ 0x1BD11BDAu;
  x0 += k0; x1 += k1;
#define TF_R(r) { x0 += x1; x1 = (x1 << (r)) | (x1 >> (32 - (r))); x1 ^= x0; }
  TF_R(13) TF_R(15) TF_R(26) TF_R(6)
  x0 += k1; x1 += k2 + 1u;
  TF_R(17) TF_R(29) TF_R(16) TF_R(24)
  x0 += k2; x1 += k0 + 2u;
  TF_R(13) TF_R(15) TF_R(26) TF_R(6)
  x0 += k0; x1 += k1 + 3u;
  TF_R(17) TF_R(29) TF_R(16) TF_R(24)
  x0 += k1; x1 += k2 + 4u;
  TF_R(13) TF_R(15) TF_R(26) TF_R(6)
  x0 += k2; x1 += k0 + 5u;
#undef TF_R
  o0 = x0; o1 = x1;
}

__device__ __forceinline__ uint32_t rb32(uint32_t ka, uint32_t kb) {
  uint32_t o0, o1;
  tf_block(ka, kb, 0u, 0u, o0, o1);
  return o0 ^ o1;
}

__device__ __forceinline__ float u01(uint32_t bits) {
  uint32_t fb = (bits >> 9) | 0x3F800000u;
  return __uint_as_float(fb) - 1.0f;
}

// XLA f32 ErfInv polynomial (Giles); feeds the normal draw -> accept/reject critical
__device__ __forceinline__ float erfinv_xla(float x) {
  float w = -flog1p(-(x * x));
  float p;
  if (w < 5.0f) {
    w = w - 2.5f;
    p = 2.81022636e-08f;
    p = 3.43273939e-07f + p * w;
    p = -3.5233877e-06f + p * w;
    p = -4.39150654e-06f + p * w;
    p = 0.00021858087f + p * w;
    p = -0.00125372503f + p * w;
    p = -0.00417768164f + p * w;
    p = 0.246640727f + p * w;
    p = 1.50140941f + p * w;
  } else {
    w = sqrtf(w) - 3.0f;
    p = -0.000200214257f;
    p = 0.000100950558f + p * w;
    p = 0.00134934322f + p * w;
    p = -0.00367342844f + p * w;
    p = 0.00573950773f + p * w;
    p = -0.0076224613f + p * w;
    p = 0.00943887047f + p * w;
    p = 1.00167406f + p * w;
    p = 2.83297682f + p * w;
  }
  return p * x;
}

__device__ __forceinline__ float normal_jax(uint32_t ka, uint32_t kb) {
  float f = u01(rb32(ka, kb));
  float u = f * 2.0f + (-0.99999994f);
  u = fmaxf(-0.99999994f, u);
  return 1.41421356f * erfinv_xla(u);
}

// ---------------- Kernel 1: LMMSE prep (1 block, Woodbury 16x16) ----------------
__global__ __launch_bounds__(256) void prep_kernel(const float* __restrict__ H,
                                                   const float* __restrict__ alpha,
                                                   char* __restrict__ ws) {
  float* m    = (float*)(ws + WS_M);
  float* EY   = (float*)(ws + WS_EY);
  float* gain = (float*)(ws + WS_GAIN);
  float* scal = (float*)(ws + WS_SCAL);
  float* Gws  = (float*)(ws + WS_G);

  __shared__ float sH[128 * 16];
  __shared__ float sC[16][16];
  __shared__ float sHC[128 * 16];
  __shared__ float sm[16];
  __shared__ double sHtH[16][16];
  __shared__ double M[16][33];
  __shared__ double dfac[16];
  __shared__ double spiv;
  __shared__ int   spivrow;
  __shared__ float sgain[16 * 128];

  int t = threadIdx.x;
  for (int i = t; i < 2048; i += 256) sH[i] = H[i];
  __syncthreads();

  if (t == 0) {
    float a0 = 0.0f;
    for (int j = 0; j < 16; ++j) a0 += alpha[j];
    float pc = lgammaf(a0);
    for (int j = 0; j < 16; ++j) pc -= lgammaf(alpha[j]);
    scal[2] = a0; scal[1] = pc;
    for (int j = 0; j < 16; ++j) { sm[j] = alpha[j] / a0; m[j] = sm[j]; }
  }
  __syncthreads();
  float a0 = scal[2];

  {
    int i = t >> 4, j = t & 15;
    float v = ((i == j) ? sm[i] : 0.0f) - sm[i] * sm[j];
    sC[i][j] = v / (a0 + 1.0f);
  }
  if (t < 128) {
    float acc = 0.0f;
    for (int j = 0; j < 16; ++j) acc += sH[t * 16 + j] * sm[j];
    EY[t] = acc;
  }
  __syncthreads();

  for (int idx = t; idx < 2048; idx += 256) {
    int dd = idx >> 4, j = idx & 15;
    float acc = 0.0f;
    for (int i = 0; i < 16; ++i) acc += sH[dd * 16 + i] * sC[i][j];
    sHC[idx] = acc;
  }
  {
    int i = t >> 4, j = t & 15;
    double acc = 0.0;
    for (int dd = 0; dd < 128; ++dd)
      acc += (double)sH[dd * 16 + i] * (double)sH[dd * 16 + j];
    sHtH[i][j] = acc;
    Gws[i * 16 + j] = (float)acc;     // G for the main-kernel quadratic form
  }
  __syncthreads();

  {
    int i = t >> 4, j = t & 15;
    double acc = (i == j) ? 0.01 : 0.0;
    for (int k = 0; k < 16; ++k) acc += (double)sC[i][k] * sHtH[k][j];
    M[i][j] = acc;
    M[i][16 + j] = (i == j) ? 1.0 : 0.0;
  }
  __syncthreads();

  for (int p = 0; p < 16; ++p) {
    if (t == 0) {
      int best = p; double bv = fabs(M[p][p]);
      for (int r = p + 1; r < 16; ++r) {
        double v = fabs(M[r][p]);
        if (v > bv) { bv = v; best = r; }
      }
      spivrow = best;
    }
    __syncthreads();
    int pr = spivrow;
    double va = 0.0, vb = 0.0;
    if (t < 32 && pr != p) { va = M[p][t]; vb = M[pr][t]; }
    __syncthreads();
    if (t < 32 && pr != p) { M[p][t] = vb; M[pr][t] = va; }
    __syncthreads();
    if (t == 0) spiv = 1.0 / M[p][p];
    __syncthreads();
    if (t < 32) M[p][t] *= spiv;
    if (t < 16) dfac[t] = M[t][p];
    __syncthreads();
    for (int e = t; e < 512; e += 256) {
      int r = e >> 5, c = e & 31;
      if (r != p) M[r][c] -= dfac[r] * M[p][c];
    }
    __syncthreads();
  }

  for (int idx = t; idx < 2048; idx += 256) {
    int j = idx >> 7, dd = idx & 127;
    double acc = 0.0;
    for (int k = 0; k < 16; ++k) acc += M[j][16 + k] * (double)sHC[dd * 16 + k];
    float g = (float)acc;
    sgain[j * 128 + dd] = g;
    gain[j * 128 + dd] = g;
  }
  __syncthreads();

  if (t == 0) {
    float tr = 0.0f;
    for (int j = 0; j < 16; ++j) {
      float s2 = 0.0f;
      for (int dd = 0; dd < 128; ++dd) s2 += sgain[j * 128 + dd] * sHC[dd * 16 + j];
      tr += sC[j][j] - s2;
    }
    tr = fmaxf(tr, 0.0f) + 1e-6f;
    scal[0] = tr;
  }
}

// ---------------- Kernel 2: per-n concentrations + u_n = H^T y_n + folded const ----------------
__global__ __launch_bounds__(256) void diri_kernel(const float* __restrict__ y,
                                                   const float* __restrict__ H,
                                                   char* __restrict__ ws) {
  float* m    = (float*)(ws + WS_M);
  float* EY   = (float*)(ws + WS_EY);
  float* gain = (float*)(ws + WS_GAIN);
  float* scal = (float*)(ws + WS_SCAL);
  float* diri = (float*)(ws + WS_DIRI);
  float* cns  = (float*)(ws + WS_QC);
  float* Uws  = (float*)(ws + WS_U);

  __shared__ float sg[16 * 128];
  __shared__ float sH[128 * 16];
  __shared__ float sEY[128];
  __shared__ float sm[16];
  __shared__ float s_tr, s_pc;

  int t = threadIdx.x;
  for (int i = t; i < 2048; i += 256) { sg[i] = gain[i]; sH[i] = H[i]; }
  if (t < 128) sEY[t] = EY[t];
  if (t < 16) sm[t] = m[t];
  if (t == 0) { s_tr = scal[0]; s_pc = scal[1]; }
  __syncthreads();

  int n = blockIdx.x * 256 + t;
  float tv[16], u[16];
#pragma unroll
  for (int j = 0; j < 16; ++j) { tv[j] = sm[j]; u[j] = 0.0f; }
  float yy = 0.0f;
  const float* yn = y + n * 128;
  for (int dd = 0; dd < 128; ++dd) {
    float yv = yn[dd];
    float dy = yv - sEY[dd];
    yy += yv * yv;
#pragma unroll
    for (int j = 0; j < 16; ++j) {
      tv[j] += dy * sg[j * 128 + dd];
      u[j]  += yv * sH[dd * 16 + j];
    }
  }
  float s = 0.0f;
#pragma unroll
  for (int j = 0; j < 16; ++j) { tv[j] = fmaxf(tv[j], 0.0f) + 1e-6f; s += tv[j]; }
  float ssq = 0.0f;
#pragma unroll
  for (int j = 0; j < 16; ++j) { tv[j] = tv[j] / s; ssq += tv[j] * tv[j]; }
  float k = (1.0f - ssq) / s_tr - 1.0f;
  float dsum = 0.0f, lgs = 0.0f;
  float* dn = diri + n * 16;
#pragma unroll
  for (int j = 0; j < 16; ++j) {
    float dj = fmaxf(k * tv[j], 0.0f) + 0.8f;
    dn[j] = dj; dsum += dj; lgs += lgammaf(dj);
    Uws[n * 16 + j] = u[j];
  }
  float qcn = lgammaf(dsum) - lgs;
  cns[n] = s_pc - qcn - 50.0f * yy;     // lw = -50*(zGz-2zu) + (p2-q) + cn
}

// ---------------- Kernel 3: sampling + importance-weighted moments ----------------
// Phase 1: self-paced per-lane rejection sampling (reject pooling via flattened
// state machine; Threefry chain per sample is bit-identical to the lockstep
// version, only the wave schedule changes). Phase 2: round-5 consumption.
__global__ __launch_bounds__(256) void main_kernel(const float* __restrict__ alpha,
                                                   const char* __restrict__ ws,
                                                   float* __restrict__ out) {
  const float* diri = (const float*)(ws + WS_DIRI);
  const float* cns  = (const float*)(ws + WS_QC);
  const float* Uw   = (const float*)(ws + WS_U);
  const float* Gw   = (const float*)(ws + WS_G);

  __shared__ float slg_all[32][256];   // lg for all chunks (32 KB)
  __shared__ float sz[16][17];
  __shared__ float slw[16], swv[16];
  __shared__ float sM, sS, sFac;

  int t = threadIdx.x;
  int n = blockIdx.x;
  int h_sub = t >> 4, j = t & 15;

  float aj = diri[n * 16 + j];

  // ---- Phase 1: generate all of this lane's samples, self-paced ----
  {
    bool boost = (aj >= 1.0f);
    float aa = boost ? aj : (aj + 1.0f);
    float d  = aa - 0.33333334f;
    float cc = 0.33333334f / sqrtf(d);
    float inv_a = 1.0f / aj;
    int numc = (h_sub < 4) ? 32 : 31;        // h = 16c+h_sub < 500
    int c = 0;
    bool need_init = true;
    bool pending = true;
    uint32_t kcx = 0, kcy = 0;
    float log_samples = 0.0f;

    while (__ballot(pending)) {
      if (pending) {
        if (need_init) {
          int h = c * 16 + h_sub;
          uint32_t jf = (((uint32_t)h * 2048u + (uint32_t)n) << 4) | (uint32_t)j;
          uint32_t ka, kb, ska, skb;
          tf_block(0u, 42u, 0u, jf, ka, kb);     // per-sample key (foldlike split)
          tf_block(ka, kb, 0u, 0u, kcx, kcy);    // carried key
          tf_block(ka, kb, 0u, 1u, ska, skb);    // subkey -> exponential
          float ef = u01(rb32(ska, skb));
          log_samples = log1pf(-ef);             // continuous -> f32
          need_init = false;
        }
        // one Marsaglia-Tsang outer iteration
        uint32_t xka, xkb, Uka, Ukb;
        tf_block(kcx, kcy, 0u, 1u, xka, xkb);    // x_key
        tf_block(kcx, kcy, 0u, 2u, Uka, Ukb);    // U_key
        float x = 0.0f, v = -1.0f;
        for (int in = 0; in < 256; ++in) {
          uint32_t sxa, sxb;
          tf_block(xka, xkb, 0u, 1u, sxa, sxb);  // subkey for normal
          x = normal_jax(sxa, sxb);
          v = 1.0f + x * cc;
          if (v > 0.0f) break;
          uint32_t nxa, nxb;
          tf_block(xka, xkb, 0u, 0u, nxa, nxb);  // lazy inner carry
          xka = nxa; xkb = nxb;
        }
        float X = x * x;
        float V = (v * v) * v;
        float U = u01(rb32(Uka, Ukb));
        // continue while BOTH hold; accept when either fails (f64-path logs)
        bool cont = (U >= 1.0f - 0.0331f * (X * X));
        if (cont) cont = (flog(U) >= X * 0.5f + d * ((1.0f - V) + flog(V)));
        if (cont) {
          uint32_t kna, knb;
          tf_block(kcx, kcy, 0u, 0u, kna, knb);  // lazy outer carry
          kcx = kna; kcy = knb;
        } else {
          float log_boost = (boost || log_samples == 0.0f)
                              ? 0.0f : log_samples * inv_a;
          slg_all[c][t] = (logf(d) + logf(V)) + log_boost;  // continuous -> f32
          ++c;
          need_init = true;
          pending = (c < numc);
        }
      }
    }
  }

  // ---- Phase 2: softmax + importance weights + moment accumulation ----
  float Greg[16];
#pragma unroll
  for (int k = 0; k < 16; ++k) Greg[k] = Gw[j * 16 + k];
  float uj2  = 2.0f * Uw[n * 16 + j];
  float cn   = cns[n];
  float admj = alpha[j] - aj;          // (alpha_j-1)-(diri_j-1): merged p2-q coeff
  if (t == 0) { sM = -INFINITY; sS = 0.0f; sFac = 1.0f; }
  __syncthreads();   // slg_all complete + sM init

  float acc = 0.0f;     // zzy[k=h_sub][l=j]
  float zyacc = 0.0f;   // threads t<16 own zy[t]

  for (int cch = 0; cch < 32; ++cch) {
    int h = cch * 16 + h_sub;
    bool valid = (h < NSAMP);
    float lg = slg_all[cch][t];

    // row softmax via intra-wave shuffles (row = 16 contiguous lanes)
    float mx = lg;
    mx = fmaxf(mx, __shfl_xor(mx, 1, 16));
    mx = fmaxf(mx, __shfl_xor(mx, 2, 16));
    mx = fmaxf(mx, __shfl_xor(mx, 4, 16));
    mx = fmaxf(mx, __shfl_xor(mx, 8, 16));
    float ez = expf(lg - mx);
    float se = ez;
    se += __shfl_xor(se, 1, 16);
    se += __shfl_xor(se, 2, 16);
    se += __shfl_xor(se, 4, 16);
    se += __shfl_xor(se, 8, 16);
    float z = valid ? (ez / se) : 0.0f;
    sz[h_sub][j] = z;                      // same-wave readers below
    float lz = logf(z);
    float pq = admj * lz;                  // p2 - q contribution

    // quadratic form: (Gz)_j then z_j*((Gz)_j - 2u_j)
    float gz = 0.0f;
#pragma unroll
    for (int k = 0; k < 16; ++k) gz = fmaf(Greg[k], sz[h_sub][k], gz);
    float sres = z * (gz - uj2);

    pq   += __shfl_xor(pq, 1, 16);
    pq   += __shfl_xor(pq, 2, 16);
    pq   += __shfl_xor(pq, 4, 16);
    pq   += __shfl_xor(pq, 8, 16);
    sres += __shfl_xor(sres, 1, 16);
    sres += __shfl_xor(sres, 2, 16);
    sres += __shfl_xor(sres, 4, 16);
    sres += __shfl_xor(sres, 8, 16);

    if (j == 0) {
      float lw = -50.0f * sres + pq + cn;
      slw[h_sub] = valid ? lw : -INFINITY;
    }
    __syncthreads();   // B1: slw + all rows' sz visible

    if (t < 16) {
      float cmax = sM;
      for (int hh = 0; hh < 16; ++hh) cmax = fmaxf(cmax, slw[hh]);
      float w = expf(slw[t] - cmax);
      swv[t] = w;
      if (t == 0) {
        float f2 = expf(sM - cmax);
        float Snew = sS * f2;
        for (int hh = 0; hh < 16; ++hh) Snew += swv[hh];
        sM = cmax; sS = Snew; sFac = f2;
      }
    }
    __syncthreads();   // B2: swv, sFac visible

    float fc = sFac;
    acc *= fc;
#pragma unroll
    for (int hh = 0; hh < 16; ++hh)
      acc = fmaf(swv[hh] * sz[hh][h_sub], sz[hh][j], acc);
    if (t < 16) {
      zyacc *= fc;
#pragma unroll
      for (int hh = 0; hh < 16; ++hh) zyacc = fmaf(swv[hh], sz[hh][t], zyacc);
    }
    __syncthreads();   // B3: protect sz from next chunk's overwrite
  }

  float Sf = sS;
  if (t < 16) out[n * 16 + t] = zyacc / Sf;
  out[N_OBS * R_DIM + n * 256 + t] = acc / Sf;
}

extern "C" void kernel_launch(void* const* d_in, const int* in_sizes, int n_in,
                              void* d_out, int out_size, void* d_ws, size_t ws_size,
                              hipStream_t stream) {
  const float* y     = (const float*)d_in[0];
  const float* H     = (const float*)d_in[1];
  const float* alpha = (const float*)d_in[2];
  char* ws = (char*)d_ws;
  float* out = (float*)d_out;

  prep_kernel<<<1, 256, 0, stream>>>(H, alpha, ws);
  diri_kernel<<<8, 256, 0, stream>>>(y, H, ws);
  main_kernel<<<N_OBS, 256, 0, stream>>>(alpha, ws, out);
}

// Round 7
// 629.290 us; speedup vs baseline: 10.0779x; 1.1120x over previous
//
#include <hip/hip_runtime.h>
#include <cstdint>
#include <cmath>

#pragma clang fp contract(off)

#define N_OBS 2048
#define D_DIM 128
#define R_DIM 16
#define NSAMP 500

// ---- workspace layout (bytes) ----
#define WS_M     0        // 16 f32
#define WS_EY    64       // 128 f32
#define WS_GAIN  576      // 16*128 f32
#define WS_SCAL  8768     // scalars: [0]=trace_C, [1]=pconst, [2]=alpha0
#define WS_G     8800     // 16*16 f32  G = H^T H
#define WS_DIRI  279136   // 2048*16 f32
#define WS_QC    410208   // 2048 f32: folded const c_n = spc - qc_n - 50*||y_n||^2
#define WS_U     418400   // 2048*16 f32: u_n = H^T y_n

// ---- f64-path f32 transcendentals: accept/reject-critical values only.
// Matching glibc/XLA-CPU rounding keeps the rejection stream aligned (round-2
// lesson). Round-7: the acceptance test is margin-gated — f32 fast path with a
// provably-conservative error bound, f64 fallback near the boundary.
__device__ __forceinline__ float flog(float x)   { return (float)log((double)x); }
__device__ __forceinline__ float flog1p(float x) { return (float)log1p((double)x); }

// ---------------- Threefry-2x32, 20 rounds (JAX-compatible) ----------------
__device__ __forceinline__ void tf_block(uint32_t k0, uint32_t k1,
                                         uint32_t x0, uint32_t x1,
                                         uint32_t& o0, uint32_t& o1) {
  const uint32_t k2 = k0 ^ k1 ^ 0x1BD11BDAu;
  x0 += k0; x1 += k1;
#define TF_R(r) { x0 += x1; x1 = (x1 << (r)) | (x1 >> (32 - (r))); x1 ^= x0; }
  TF_R(13) TF_R(15) TF_R(26) TF_R(6)
  x0 += k1; x1 += k2 + 1u;
  TF_R(17) TF_R(29) TF_R(16) TF_R(24)
  x0 += k2; x1 += k0 + 2u;
  TF_R(13) TF_R(15) TF_R(26) TF_R(6)
  x0 += k0; x1 += k1 + 3u;
  TF_R(17) TF_R(29) TF_R(16) TF_R(24)
  x0 += k1; x1 += k2 + 4u;
  TF_R(13) TF_R(15) TF_R(26) TF_R(6)
  x0 += k2; x1 += k0 + 5u;
#undef TF_R
  o0 = x0; o1 = x1;
}

__device__ __forceinline__ uint32_t rb32(uint32_t ka, uint32_t kb) {
  uint32_t o0, o1;
  tf_block(ka, kb, 0u, 0u, o0, o1);
  return o0 ^ o1;
}

__device__ __forceinline__ float u01(uint32_t bits) {
  uint32_t fb = (bits >> 9) | 0x3F800000u;
  return __uint_as_float(fb) - 1.0f;
}

// XLA f32 ErfInv polynomial (Giles); feeds the normal draw -> value must match
// the reference bitwise, so its log1p stays on the f64 path (not gateable).
__device__ __forceinline__ float erfinv_xla(float x) {
  float w = -flog1p(-(x * x));
  float p;
  if (w < 5.0f) {
    w = w - 2.5f;
    p = 2.81022636e-08f;
    p = 3.43273939e-07f + p * w;
    p = -3.5233877e-06f + p * w;
    p = -4.39150654e-06f + p * w;
    p = 0.00021858087f + p * w;
    p = -0.00125372503f + p * w;
    p = -0.00417768164f + p * w;
    p = 0.246640727f + p * w;
    p = 1.50140941f + p * w;
  } else {
    w = sqrtf(w) - 3.0f;
    p = -0.000200214257f;
    p = 0.000100950558f + p * w;
    p = 0.00134934322f + p * w;
    p = -0.00367342844f + p * w;
    p = 0.00573950773f + p * w;
    p = -0.0076224613f + p * w;
    p = 0.00943887047f + p * w;
    p = 1.00167406f + p * w;
    p = 2.83297682f + p * w;
  }
  return p * x;
}

__device__ __forceinline__ float normal_jax(uint32_t ka, uint32_t kb) {
  float f = u01(rb32(ka, kb));
  float u = f * 2.0f + (-0.99999994f);
  u = fmaxf(-0.99999994f, u);
  return 1.41421356f * erfinv_xla(u);
}

// ---------------- Kernel 1: LMMSE prep (1 block, Woodbury 16x16) ----------------
__global__ __launch_bounds__(256) void prep_kernel(const float* __restrict__ H,
                                                   const float* __restrict__ alpha,
                                                   char* __restrict__ ws) {
  float* m    = (float*)(ws + WS_M);
  float* EY   = (float*)(ws + WS_EY);
  float* gain = (float*)(ws + WS_GAIN);
  float* scal = (float*)(ws + WS_SCAL);
  float* Gws  = (float*)(ws + WS_G);

  __shared__ float sH[128 * 16];
  __shared__ float sC[16][16];
  __shared__ float sHC[128 * 16];
  __shared__ float sm[16];
  __shared__ double sHtH[16][16];
  __shared__ double M[16][33];
  __shared__ double dfac[16];
  __shared__ double spiv;
  __shared__ int   spivrow;
  __shared__ float sgain[16 * 128];

  int t = threadIdx.x;
  for (int i = t; i < 2048; i += 256) sH[i] = H[i];
  __syncthreads();

  if (t == 0) {
    float a0 = 0.0f;
    for (int j = 0; j < 16; ++j) a0 += alpha[j];
    float pc = lgammaf(a0);
    for (int j = 0; j < 16; ++j) pc -= lgammaf(alpha[j]);
    scal[2] = a0; scal[1] = pc;
    for (int j = 0; j < 16; ++j) { sm[j] = alpha[j] / a0; m[j] = sm[j]; }
  }
  __syncthreads();
  float a0 = scal[2];

  {
    int i = t >> 4, j = t & 15;
    float v = ((i == j) ? sm[i] : 0.0f) - sm[i] * sm[j];
    sC[i][j] = v / (a0 + 1.0f);
  }
  if (t < 128) {
    float acc = 0.0f;
    for (int j = 0; j < 16; ++j) acc += sH[t * 16 + j] * sm[j];
    EY[t] = acc;
  }
  __syncthreads();

  for (int idx = t; idx < 2048; idx += 256) {
    int dd = idx >> 4, j = idx & 15;
    float acc = 0.0f;
    for (int i = 0; i < 16; ++i) acc += sH[dd * 16 + i] * sC[i][j];
    sHC[idx] = acc;
  }
  {
    int i = t >> 4, j = t & 15;
    double acc = 0.0;
    for (int dd = 0; dd < 128; ++dd)
      acc += (double)sH[dd * 16 + i] * (double)sH[dd * 16 + j];
    sHtH[i][j] = acc;
    Gws[i * 16 + j] = (float)acc;     // G for the main-kernel quadratic form
  }
  __syncthreads();

  {
    int i = t >> 4, j = t & 15;
    double acc = (i == j) ? 0.01 : 0.0;
    for (int k = 0; k < 16; ++k) acc += (double)sC[i][k] * sHtH[k][j];
    M[i][j] = acc;
    M[i][16 + j] = (i == j) ? 1.0 : 0.0;
  }
  __syncthreads();

  for (int p = 0; p < 16; ++p) {
    if (t == 0) {
      int best = p; double bv = fabs(M[p][p]);
      for (int r = p + 1; r < 16; ++r) {
        double v = fabs(M[r][p]);
        if (v > bv) { bv = v; best = r; }
      }
      spivrow = best;
    }
    __syncthreads();
    int pr = spivrow;
    double va = 0.0, vb = 0.0;
    if (t < 32 && pr != p) { va = M[p][t]; vb = M[pr][t]; }
    __syncthreads();
    if (t < 32 && pr != p) { M[p][t] = vb; M[pr][t] = va; }
    __syncthreads();
    if (t == 0) spiv = 1.0 / M[p][p];
    __syncthreads();
    if (t < 32) M[p][t] *= spiv;
    if (t < 16) dfac[t] = M[t][p];
    __syncthreads();
    for (int e = t; e < 512; e += 256) {
      int r = e >> 5, c = e & 31;
      if (r != p) M[r][c] -= dfac[r] * M[p][c];
    }
    __syncthreads();
  }

  for (int idx = t; idx < 2048; idx += 256) {
    int j = idx >> 7, dd = idx & 127;
    double acc = 0.0;
    for (int k = 0; k < 16; ++k) acc += M[j][16 + k] * (double)sHC[dd * 16 + k];
    float g = (float)acc;
    sgain[j * 128 + dd] = g;
    gain[j * 128 + dd] = g;
  }
  __syncthreads();

  if (t == 0) {
    float tr = 0.0f;
    for (int j = 0; j < 16; ++j) {
      float s2 = 0.0f;
      for (int dd = 0; dd < 128; ++dd) s2 += sgain[j * 128 + dd] * sHC[dd * 16 + j];
      tr += sC[j][j] - s2;
    }
    tr = fmaxf(tr, 0.0f) + 1e-6f;
    scal[0] = tr;
  }
}

// ---------------- Kernel 2: per-n concentrations + u_n = H^T y_n + folded const ----------------
__global__ __launch_bounds__(256) void diri_kernel(const float* __restrict__ y,
                                                   const float* __restrict__ H,
                                                   char* __restrict__ ws) {
  float* m    = (float*)(ws + WS_M);
  float* EY   = (float*)(ws + WS_EY);
  float* gain = (float*)(ws + WS_GAIN);
  float* scal = (float*)(ws + WS_SCAL);
  float* diri = (float*)(ws + WS_DIRI);
  float* cns  = (float*)(ws + WS_QC);
  float* Uws  = (float*)(ws + WS_U);

  __shared__ float sg[16 * 128];
  __shared__ float sH[128 * 16];
  __shared__ float sEY[128];
  __shared__ float sm[16];
  __shared__ float s_tr, s_pc;

  int t = threadIdx.x;
  for (int i = t; i < 2048; i += 256) { sg[i] = gain[i]; sH[i] = H[i]; }
  if (t < 128) sEY[t] = EY[t];
  if (t < 16) sm[t] = m[t];
  if (t == 0) { s_tr = scal[0]; s_pc = scal[1]; }
  __syncthreads();

  int n = blockIdx.x * 256 + t;
  float tv[16], u[16];
#pragma unroll
  for (int j = 0; j < 16; ++j) { tv[j] = sm[j]; u[j] = 0.0f; }
  float yy = 0.0f;
  const float* yn = y + n * 128;
  for (int dd = 0; dd < 128; ++dd) {
    float yv = yn[dd];
    float dy = yv - sEY[dd];
    yy += yv * yv;
#pragma unroll
    for (int j = 0; j < 16; ++j) {
      tv[j] += dy * sg[j * 128 + dd];
      u[j]  += yv * sH[dd * 16 + j];
    }
  }
  float s = 0.0f;
#pragma unroll
  for (int j = 0; j < 16; ++j) { tv[j] = fmaxf(tv[j], 0.0f) + 1e-6f; s += tv[j]; }
  float ssq = 0.0f;
#pragma unroll
  for (int j = 0; j < 16; ++j) { tv[j] = tv[j] / s; ssq += tv[j] * tv[j]; }
  float k = (1.0f - ssq) / s_tr - 1.0f;
  float dsum = 0.0f, lgs = 0.0f;
  float* dn = diri + n * 16;
#pragma unroll
  for (int j = 0; j < 16; ++j) {
    float dj = fmaxf(k * tv[j], 0.0f) + 0.8f;
    dn[j] = dj; dsum += dj; lgs += lgammaf(dj);
    Uws[n * 16 + j] = u[j];
  }
  float qcn = lgammaf(dsum) - lgs;
  cns[n] = s_pc - qcn - 50.0f * yy;     // lw = -50*(zGz-2zu) + (p2-q) + cn
}

// ---------------- Kernel 3: sampling + importance-weighted moments ----------------
__global__ __launch_bounds__(256) void main_kernel(const float* __restrict__ alpha,
                                                   const char* __restrict__ ws,
                                                   float* __restrict__ out) {
  const float* diri = (const float*)(ws + WS_DIRI);
  const float* cns  = (const float*)(ws + WS_QC);
  const float* Uw   = (const float*)(ws + WS_U);
  const float* Gw   = (const float*)(ws + WS_G);

  __shared__ float slg_all[32][256];   // lg for all chunks (32 KB)
  __shared__ float sz[16][17];
  __shared__ float slw[16], swv[16];
  __shared__ float sM, sS, sFac;

  int t = threadIdx.x;
  int n = blockIdx.x;
  int h_sub = t >> 4, j = t & 15;

  float aj = diri[n * 16 + j];

  // ---- Phase 1: generate all of this lane's samples, self-paced ----
  {
    bool boost = (aj >= 1.0f);
    float aa = boost ? aj : (aj + 1.0f);
    float d  = aa - 0.33333334f;
    float cc = 0.33333334f / sqrtf(d);
    float inv_a = 1.0f / aj;
    float ld32 = logf(d);                    // loop-invariant (accept-path value)
    int numc = (h_sub < 4) ? 32 : 31;        // h = 16c+h_sub < 500
    int c = 0;
    bool need_init = true;
    bool pending = true;
    uint32_t kcx = 0, kcy = 0;
    float log_samples = 0.0f;

    while (__ballot(pending)) {
      if (pending) {
        if (need_init) {
          int h = c * 16 + h_sub;
          uint32_t jf = (((uint32_t)h * 2048u + (uint32_t)n) << 4) | (uint32_t)j;
          uint32_t ka, kb, ska, skb;
          tf_block(0u, 42u, 0u, jf, ka, kb);     // per-sample key (foldlike split)
          tf_block(ka, kb, 0u, 0u, kcx, kcy);    // carried key
          tf_block(ka, kb, 0u, 1u, ska, skb);    // subkey -> exponential
          float ef = u01(rb32(ska, skb));
          log_samples = log1pf(-ef);             // continuous -> f32
          need_init = false;
        }
        // one Marsaglia-Tsang outer iteration
        uint32_t xka, xkb, Uka, Ukb;
        tf_block(kcx, kcy, 0u, 1u, xka, xkb);    // x_key
        tf_block(kcx, kcy, 0u, 2u, Uka, Ukb);    // U_key
        float x = 0.0f, v = -1.0f;
        for (int in = 0; in < 256; ++in) {
          uint32_t sxa, sxb;
          tf_block(xka, xkb, 0u, 1u, sxa, sxb);  // subkey for normal
          x = normal_jax(sxa, sxb);
          v = 1.0f + x * cc;
          if (v > 0.0f) break;
          uint32_t nxa, nxb;
          tf_block(xka, xkb, 0u, 0u, nxa, nxb);  // lazy inner carry
          xka = nxa; xkb = nxb;
        }
        float X = x * x;
        float V = (v * v) * v;
        float U = u01(rb32(Uka, Ukb));
        float lv32 = logf(V);                    // test fast-path + accept output
        // continue while BOTH hold; accept when either fails.
        bool cont = (U >= 1.0f - 0.0331f * (X * X));
        if (cont) {
          // margin-gated log test: f32 fast path, f64 fallback at the boundary.
          float lu32  = logf(U);
          float rhs32 = X * 0.5f + d * ((1.0f - V) + lv32);
          float margin = lu32 - rhs32;
          float thr = 4.8e-7f * fabsf(lu32)
                    + 4.8e-7f * d * fabsf(lv32)
                    + 1.2e-7f * (fabsf(rhs32) + X)
                    + 1e-7f;
          if (fabsf(margin) > thr) {
            cont = (margin >= 0.0f);
          } else {
            cont = (flog(U) >= X * 0.5f + d * ((1.0f - V) + flog(V)));
          }
        }
        if (cont) {
          uint32_t kna, knb;
          tf_block(kcx, kcy, 0u, 0u, kna, knb);  // lazy outer carry
          kcx = kna; kcy = knb;
        } else {
          float log_boost = (boost || log_samples == 0.0f)
                              ? 0.0f : log_samples * inv_a;
          slg_all[c][t] = (ld32 + lv32) + log_boost;  // == (logf(d)+logf(V))+boost
          ++c;
          need_init = true;
          pending = (c < numc);
        }
      }
    }
  }

  // ---- Phase 2: softmax + importance weights + moment accumulation ----
  float Greg[16];
#pragma unroll
  for (int k = 0; k < 16; ++k) Greg[k] = Gw[j * 16 + k];
  float uj2  = 2.0f * Uw[n * 16 + j];
  float cn   = cns[n];
  float admj = alpha[j] - aj;          // (alpha_j-1)-(diri_j-1): merged p2-q coeff
  if (t == 0) { sM = -INFINITY; sS = 0.0f; sFac = 1.0f; }
  __syncthreads();   // slg_all complete + sM init

  float acc = 0.0f;     // zzy[k=h_sub][l=j]
  float zyacc = 0.0f;   // threads t<16 own zy[t]

  for (int cch = 0; cch < 32; ++cch) {
    int h = cch * 16 + h_sub;
    bool valid = (h < NSAMP);
    float lg = slg_all[cch][t];

    // row softmax via intra-wave shuffles (row = 16 contiguous lanes)
    float mx = lg;
    mx = fmaxf(mx, __shfl_xor(mx, 1, 16));
    mx = fmaxf(mx, __shfl_xor(mx, 2, 16));
    mx = fmaxf(mx, __shfl_xor(mx, 4, 16));
    mx = fmaxf(mx, __shfl_xor(mx, 8, 16));
    float ez = expf(lg - mx);
    float se = ez;
    se += __shfl_xor(se, 1, 16);
    se += __shfl_xor(se, 2, 16);
    se += __shfl_xor(se, 4, 16);
    se += __shfl_xor(se, 8, 16);
    float z = valid ? (ez / se) : 0.0f;
    sz[h_sub][j] = z;                      // same-wave readers below
    float lz = logf(z);
    float pq = admj * lz;                  // p2 - q contribution

    // quadratic form: (Gz)_j then z_j*((Gz)_j - 2u_j)
    float gz = 0.0f;
#pragma unroll
    for (int k = 0; k < 16; ++k) gz = fmaf(Greg[k], sz[h_sub][k], gz);
    float sres = z * (gz - uj2);

    pq   += __shfl_xor(pq, 1, 16);
    pq   += __shfl_xor(pq, 2, 16);
    pq   += __shfl_xor(pq, 4, 16);
    pq   += __shfl_xor(pq, 8, 16);
    sres += __shfl_xor(sres, 1, 16);
    sres += __shfl_xor(sres, 2, 16);
    sres += __shfl_xor(sres, 4, 16);
    sres += __shfl_xor(sres, 8, 16);

    if (j == 0) {
      float lw = -50.0f * sres + pq + cn;
      slw[h_sub] = valid ? lw : -INFINITY;
    }
    __syncthreads();   // B1: slw + all rows' sz visible

    if (t < 16) {
      float cmax = sM;
      for (int hh = 0; hh < 16; ++hh) cmax = fmaxf(cmax, slw[hh]);
      float w = expf(slw[t] - cmax);
      swv[t] = w;
      if (t == 0) {
        float f2 = expf(sM - cmax);
        float Snew = sS * f2;
        for (int hh = 0; hh < 16; ++hh) Snew += swv[hh];
        sM = cmax; sS = Snew; sFac = f2;
      }
    }
    __syncthreads();   // B2: swv, sFac visible

    float fc = sFac;
    acc *= fc;
#pragma unroll
    for (int hh = 0; hh < 16; ++hh)
      acc = fmaf(swv[hh] * sz[hh][h_sub], sz[hh][j], acc);
    if (t < 16) {
      zyacc *= fc;
#pragma unroll
      for (int hh = 0; hh < 16; ++hh) zyacc = fmaf(swv[hh], sz[hh][t], zyacc);
    }
    __syncthreads();   // B3: protect sz from next chunk's overwrite
  }

  float Sf = sS;
  if (t < 16) out[n * 16 + t] = zyacc / Sf;
  out[N_OBS * R_DIM + n * 256 + t] = acc / Sf;
}

extern "C" void kernel_launch(void* const* d_in, const int* in_sizes, int n_in,
                              void* d_out, int out_size, void* d_ws, size_t ws_size,
                              hipStream_t stream) {
  const float* y     = (const float*)d_in[0];
  const float* H     = (const float*)d_in[1];
  const float* alpha = (const float*)d_in[2];
  char* ws = (char*)d_ws;
  float* out = (float*)d_out;

  prep_kernel<<<1, 256, 0, stream>>>(H, alpha, ws);
  diri_kernel<<<8, 256, 0, stream>>>(y, H, ws);
  main_kernel<<<N_OBS, 256, 0, stream>>>(alpha, ws, out);
}